// Round 7
// baseline (965.084 us; speedup 1.0000x reference)
//
#include <hip/hip_runtime.h>
#include <math.h>
#include <stdint.h>

// ---------------------------------------------------------------------------
// MalaAttention on MI355X (gfx950). Round 12:
//  - gemm_final: REVERT to 128x128/256-thr K-loop (round-3 config, measured
//    best total 427us); new coalesced fp32 store via float T2[32][132] LDS
//    quarter-passes (was 64 scalar dword stores/thread).
//  - gemm_num: epilogue processes row-pairs with bf16x4 (8B/lane), halving
//    epilogue loads/stores and iterations.
//  - gemm_qkvg: round-8 schedule kept (149-151us, 0 conflicts, FETCH 106MB).
//
// Workspace layout (bytes):
//   Xb    @ 0          32MB  bf16 X        (dead after proj -> kvp)
//   kvp   @ 0          32MB  f32 [16][bh][128][128] kv partials
//   Wcat  @ 33554432    8MB  bf16 [Wq;Wk;Wv;Wg]
//   Wob   @ 41943040    2MB  bf16 Wo
//   tab   @ 44040192    2MB  float2 [4096][64] rope sin/cos (dead after proj)
//   ksump @ 44040192  256KB  f32 [16][bh][128]   (aliases tab)
//   vsump @ 44302336  256KB  f32 [16][bh][128]
//   QKVG  @ 46137344  128MB  bf16 [16384][4096] col blocks: q|k|v|g
//   ksum  @ 180355072  16KB  f32 [bh][128]
//   vsum  @ 180371456  16KB  f32 [bh][128]
//   kvT   @ 180387840   1MB  bf16 kvT[bh][e][d]
//   obuf  @ 181960704  32MB  bf16 gated out
// ---------------------------------------------------------------------------

typedef __bf16 bf16;
typedef __bf16 bf16x2 __attribute__((ext_vector_type(2)));
typedef __bf16 bf16x4 __attribute__((ext_vector_type(4)));
typedef __bf16 bf16x8 __attribute__((ext_vector_type(8)));
typedef float f32x4 __attribute__((ext_vector_type(4)));

static constexpr float kScale = 0.08838834764831845f; // 1/sqrt(128)

__device__ __forceinline__ void async_copy16(const void* g, void* l) {
  __builtin_amdgcn_global_load_lds(
      (const __attribute__((address_space(1))) void*)(uintptr_t)g,
      (__attribute__((address_space(3))) void*)(uintptr_t)l, 16, 0, 0);
}

// ---------------------------------------------------------------------------
// Proj GEMM: QKVG = Xb @ Wcat^T. 256x256 tile, BK=64, 8-phase schedule.
// Grid 1024 (64 m-tiles x 16 n-tiles), XCD m-partitioned. RoPE fused (by<8).
// ---------------------------------------------------------------------------
__global__ __launch_bounds__(512, 1) void gemm_qkvg(
    const bf16* __restrict__ A, const bf16* __restrict__ Bw,
    bf16* __restrict__ C, const float2* __restrict__ tab)
{
  __shared__ __align__(16) char smem[131072];

  const int t = threadIdx.x;
  const int bid = blockIdx.x;
  const int n = bid >> 3;
  const int bx = (bid & 7) * 8 + (n & 7);         // 8 m-tiles per XCD
  const int by = n >> 3;                          // 0..15
  const long m0 = (long)bx * 256;
  const long n0 = (long)by * 256;

  const int d0 = t * 16;
  const int dd = d0 ^ (((d0 >> 7) & 7) << 4);
  const int rT = dd >> 7;
  const int cT = (dd & 127) >> 1;
  const bf16* aSt = A  + (m0 + rT) * 1024 + cT;
  const bf16* bSt = Bw + (n0 + rT) * 1024 + cT;
  char* ldsDst = smem + d0;

  const int lane = t & 63, wid = t >> 6;
  const int wm = wid >> 2, wn = wid & 3;
  const int fm = lane & 15, fq = lane >> 4;
  const int xsw = (fm & 7) << 4;
  const int o0 = (fq * 16) ^ xsw;
  const int o1 = o0 ^ 64;
  const char* ldsA0 = smem + wm * 16384 + fm * 128 + o0;
  const char* ldsA1 = smem + wm * 16384 + fm * 128 + o1;
  const char* ldsB0 = smem + 32768 + (wn >> 1) * 16384 +
                      ((wn & 1) * 64 + fm) * 128 + o0;
  const char* ldsB1 = ldsB0 + (o1 - o0);

  f32x4 acc[8][4] = {};
  bf16x8 a4[4][2], b4[4][2];

#define STAGE_A(kt, h) do {                                                  \
    const bf16* s_ = aSt + (long)(h) * 131072 + (kt) * 64;                   \
    char* d_ = ldsDst + ((kt) & 1) * 65536 + (h) * 16384;                    \
    async_copy16(s_, d_);                                                    \
    async_copy16(s_ + 65536, d_ + 8192);                                     \
  } while (0)
#define STAGE_B(kt, h) do {                                                  \
    const bf16* s_ = bSt + (long)(h) * 131072 + (kt) * 64;                   \
    char* d_ = ldsDst + ((kt) & 1) * 65536 + 32768 + (h) * 16384;            \
    async_copy16(s_, d_);                                                    \
    async_copy16(s_ + 65536, d_ + 8192);                                     \
  } while (0)
#define LOAD_A(buf, qi) do {                                                 \
    const char* p0_ = ldsA0 + (buf) * 65536 + (qi) * 8192;                   \
    const char* p1_ = ldsA1 + (buf) * 65536 + (qi) * 8192;                   \
    a4[0][0] = *(const bf16x8*)(p0_);                                        \
    a4[0][1] = *(const bf16x8*)(p1_);                                        \
    a4[1][0] = *(const bf16x8*)(p0_ + 2048);                                 \
    a4[1][1] = *(const bf16x8*)(p1_ + 2048);                                 \
    a4[2][0] = *(const bf16x8*)(p0_ + 4096);                                 \
    a4[2][1] = *(const bf16x8*)(p1_ + 4096);                                 \
    a4[3][0] = *(const bf16x8*)(p0_ + 6144);                                 \
    a4[3][1] = *(const bf16x8*)(p1_ + 6144);                                 \
  } while (0)
#define LOAD_B(buf, qj) do {                                                 \
    const char* p0_ = ldsB0 + (buf) * 65536 + (qj) * 4096;                   \
    const char* p1_ = ldsB1 + (buf) * 65536 + (qj) * 4096;                   \
    b4[2*(qj)+0][0] = *(const bf16x8*)(p0_);                                 \
    b4[2*(qj)+0][1] = *(const bf16x8*)(p1_);                                 \
    b4[2*(qj)+1][0] = *(const bf16x8*)(p0_ + 2048);                          \
    b4[2*(qj)+1][1] = *(const bf16x8*)(p1_ + 2048);                          \
  } while (0)
#define MM1(i, j, ks)                                                        \
    acc[i][j] = __builtin_amdgcn_mfma_f32_16x16x32_bf16(                     \
        a4[(i) & 3][ks], b4[j][ks], acc[i][j], 0, 0, 0)
#define MFMA_Q(qi, qj) do {                                                  \
    MM1(4*(qi)+0, 2*(qj)+0, 0); MM1(4*(qi)+1, 2*(qj)+0, 0);                  \
    MM1(4*(qi)+2, 2*(qj)+0, 0); MM1(4*(qi)+3, 2*(qj)+0, 0);                  \
    MM1(4*(qi)+0, 2*(qj)+1, 0); MM1(4*(qi)+1, 2*(qj)+1, 0);                  \
    MM1(4*(qi)+2, 2*(qj)+1, 0); MM1(4*(qi)+3, 2*(qj)+1, 0);                  \
    MM1(4*(qi)+0, 2*(qj)+0, 1); MM1(4*(qi)+1, 2*(qj)+0, 1);                  \
    MM1(4*(qi)+2, 2*(qj)+0, 1); MM1(4*(qi)+3, 2*(qj)+0, 1);                  \
    MM1(4*(qi)+0, 2*(qj)+1, 1); MM1(4*(qi)+1, 2*(qj)+1, 1);                  \
    MM1(4*(qi)+2, 2*(qj)+1, 1); MM1(4*(qi)+3, 2*(qj)+1, 1);                  \
  } while (0)
#define BAR()    __builtin_amdgcn_s_barrier()
#define SCHEDB() __builtin_amdgcn_sched_barrier(0)
#define PRIO(p)  __builtin_amdgcn_s_setprio(p)

  STAGE_A(0, 0); STAGE_A(0, 1); STAGE_B(0, 0); STAGE_B(0, 1);
  STAGE_A(1, 0);
  asm volatile("s_waitcnt vmcnt(2)" ::: "memory");
  BAR(); SCHEDB();

#pragma unroll 1
  for (int it = 0; it < 7; ++it) {
    const int k1 = 2 * it + 1;
    const int k2 = 2 * it + 2;
    const int k3 = 2 * it + 3;
    LOAD_A(0, 0); LOAD_B(0, 0);
    STAGE_A(k1, 1);
    BAR(); SCHEDB(); PRIO(1); MFMA_Q(0, 0); PRIO(0); BAR(); SCHEDB();
    LOAD_B(0, 1);
    STAGE_B(k1, 0);
    BAR(); SCHEDB(); PRIO(1); MFMA_Q(0, 1); PRIO(0); BAR(); SCHEDB();
    LOAD_A(0, 1);
    STAGE_B(k1, 1);
    BAR(); SCHEDB(); PRIO(1); MFMA_Q(1, 1); PRIO(0); BAR(); SCHEDB();
    STAGE_A(k2, 0);
    BAR(); SCHEDB(); PRIO(1); MFMA_Q(1, 0); PRIO(0);
    asm volatile("s_waitcnt vmcnt(2)" ::: "memory");
    BAR(); SCHEDB();
    LOAD_A(1, 0); LOAD_B(1, 0);
    STAGE_A(k2, 1);
    BAR(); SCHEDB(); PRIO(1); MFMA_Q(0, 0); PRIO(0); BAR(); SCHEDB();
    LOAD_B(1, 1);
    STAGE_B(k2, 0);
    BAR(); SCHEDB(); PRIO(1); MFMA_Q(0, 1); PRIO(0); BAR(); SCHEDB();
    LOAD_A(1, 1);
    STAGE_B(k2, 1);
    BAR(); SCHEDB(); PRIO(1); MFMA_Q(1, 1); PRIO(0); BAR(); SCHEDB();
    STAGE_A(k3, 0);
    BAR(); SCHEDB(); PRIO(1); MFMA_Q(1, 0); PRIO(0);
    asm volatile("s_waitcnt vmcnt(2)" ::: "memory");
    BAR(); SCHEDB();
  }

  {
    LOAD_A(0, 0); LOAD_B(0, 0);
    STAGE_A(15, 1);
    BAR(); SCHEDB(); PRIO(1); MFMA_Q(0, 0); PRIO(0); BAR(); SCHEDB();
    LOAD_B(0, 1);
    STAGE_B(15, 0);
    BAR(); SCHEDB(); PRIO(1); MFMA_Q(0, 1); PRIO(0); BAR(); SCHEDB();
    LOAD_A(0, 1);
    STAGE_B(15, 1);
    BAR(); SCHEDB(); PRIO(1); MFMA_Q(1, 1); PRIO(0); BAR(); SCHEDB();
    BAR(); SCHEDB(); PRIO(1); MFMA_Q(1, 0); PRIO(0);
    asm volatile("s_waitcnt vmcnt(0)" ::: "memory");
    BAR(); SCHEDB();
    LOAD_A(1, 0); LOAD_B(1, 0);
    BAR(); SCHEDB(); PRIO(1); MFMA_Q(0, 0); PRIO(0); BAR(); SCHEDB();
    LOAD_B(1, 1);
    BAR(); SCHEDB(); PRIO(1); MFMA_Q(0, 1); PRIO(0); BAR(); SCHEDB();
    LOAD_A(1, 1);
    BAR(); SCHEDB(); PRIO(1); MFMA_Q(1, 1); PRIO(0); BAR(); SCHEDB();
    BAR(); SCHEDB(); PRIO(1); MFMA_Q(1, 0); PRIO(0); BAR(); SCHEDB();
  }

#undef STAGE_A
#undef STAGE_B
#undef LOAD_A
#undef LOAD_B
#undef MM1
#undef MFMA_Q
#undef BAR
#undef SCHEDB
#undef PRIO

  // ---- epilogue: two 128-row half-passes through T[128][264] (RoPE by<8)
  bf16* T = (bf16*)smem;
  __syncthreads();
#pragma unroll 1
  for (int hw = 0; hw < 2; ++hw) {
    if (wm == hw) {
#pragma unroll
      for (int rf = 0; rf < 8; ++rf)
#pragma unroll
        for (int cf = 0; cf < 4; ++cf)
#pragma unroll
          for (int r = 0; r < 4; ++r)
            T[(rf * 16 + fq * 4 + r) * 264 + wn * 64 + cf * 16 + fm] =
                (bf16)acc[rf][cf][r];
    }
    __syncthreads();
    if (by < 8) {  // q|k region: RoPE pair rotation in LDS
#pragma unroll
      for (int ii = 0; ii < 32; ++ii) {
        const int pi = t + ii * 512;            // 16384 pairs
        const int row = pi >> 7, pr = pi & 127;
        const int hd = pr >> 6, i = pr & 63;
        const int c0 = hd * 128 + i;
        const int s = (int)((m0 + hw * 128 + row) & 4095);
        const float2 sc = tab[s * 64 + i];
        float x1 = (float)T[row * 264 + c0];
        float x2 = (float)T[row * 264 + c0 + 64];
        T[row * 264 + c0]      = (bf16)(x1 * sc.y - x2 * sc.x);
        T[row * 264 + c0 + 64] = (bf16)(x2 * sc.y + x1 * sc.x);
      }
      __syncthreads();
    }
#pragma unroll
    for (int ii = 0; ii < 8; ++ii) {
      const int cid = t + ii * 512;
      const int row = cid >> 5, ch = cid & 31;
      *(bf16x8*)(C + (m0 + hw * 128 + row) * 4096 + n0 + ch * 8) =
          *(const bf16x8*)(T + row * 264 + ch * 8);
    }
    __syncthreads();
  }
}

// ---------------------------------------------------------------------------
// Final NT GEMM: out = obuf @ Wo^T, fp32 out. 128x128 tile, 1D grid 1024,
// XCD-swizzled, 2 blocks/CU. Coalesced store via float T2[32][132] LDS.
// ---------------------------------------------------------------------------
__global__ __launch_bounds__(256, 2) void gemm_final(
    const bf16* __restrict__ A, const bf16* __restrict__ Bw,
    float* __restrict__ C)
{
  __shared__ __align__(16) char smem[17408];
  bf16* As = (bf16*)smem;
  bf16* Bs = (bf16*)(smem + 8192);
  const int t = threadIdx.x;
  const int bid = blockIdx.x;
  const int xcd = bid & 7, n = bid >> 3;
  const int bx = xcd * 16 + (n & 15);
  const int by = n >> 4;
  const long m0 = (long)bx * 128;
  A  += m0 * 1024;
  Bw += (long)by * 131072;
  C  += m0 * 1024 + (long)by * 128;

  const int i0 = t, i1 = t + 256;
  const bf16* gA0 = A  + (long)(i0 >> 2) * 1024 + (i0 & 3) * 8;
  const bf16* gA1 = A  + (long)(i1 >> 2) * 1024 + (i1 & 3) * 8;
  const bf16* gB0 = Bw + (long)(i0 >> 2) * 1024 + (i0 & 3) * 8;
  const bf16* gB1 = Bw + (long)(i1 >> 2) * 1024 + (i1 & 3) * 8;
  bf16* lA0 = As + i0 * 8; bf16* lA1 = As + i1 * 8;
  bf16* lB0 = Bs + i0 * 8; bf16* lB1 = Bs + i1 * 8;

  const int lane = t & 63, wv = t >> 6;
  const int moff = (wv & 1) * 64, noff = (wv >> 1) * 64;
  const int fm = lane & 15, fq = lane >> 4;

  f32x4 acc[4][4] = {};

  for (int k0 = 0; k0 < 1024; k0 += 32) {
    async_copy16(gA0, lA0); async_copy16(gA1, lA1);
    async_copy16(gB0, lB0); async_copy16(gB1, lB1);
    gA0 += 32; gA1 += 32; gB0 += 32; gB1 += 32;
    __syncthreads();
    bf16x8 af[4], bfv[4];
#pragma unroll
    for (int i = 0; i < 4; ++i) {
      af[i]  = *(const bf16x8*)(As + (moff + i * 16 + fm) * 32 + fq * 8);
      bfv[i] = *(const bf16x8*)(Bs + (noff + i * 16 + fm) * 32 + fq * 8);
    }
#pragma unroll
    for (int i = 0; i < 4; ++i)
#pragma unroll
      for (int j = 0; j < 4; ++j)
        acc[i][j] = __builtin_amdgcn_mfma_f32_16x16x32_bf16(af[i], bfv[j], acc[i][j], 0, 0, 0);
    __syncthreads();
  }

  // ---- coalesced store: 4 quarter-passes (32 rows) through T2[32][132]
  float* T2 = (float*)smem;
#pragma unroll 1
  for (int p = 0; p < 4; ++p) {
    if ((wv & 1) == (p >> 1)) {   // waves whose moff matches this quarter
      const int ib = (p & 1) * 2;
#pragma unroll
      for (int i2 = 0; i2 < 2; ++i2)
#pragma unroll
        for (int j = 0; j < 4; ++j)
#pragma unroll
          for (int r = 0; r < 4; ++r)
            T2[(i2 * 16 + fq * 4 + r) * 132 + noff + j * 16 + fm] =
                acc[ib + i2][j][r];
    }
    __syncthreads();
#pragma unroll
    for (int ii = 0; ii < 4; ++ii) {
      const int cid = t + ii * 256;           // 1024 float4 chunks
      const int row = cid >> 5, ch = cid & 31;
      *(float4*)(C + (long)(p * 32 + row) * 1024 + ch * 4) =
          *(const float4*)(T2 + row * 132 + ch * 4);
    }
    __syncthreads();
  }
}

// ---------------------------------------------------------------------------
// num GEMM (per b,h: M=4096 N=128 K=128) + fused den + mala/LePE/gate.
// Half-tile epilogue (T = 64x136); row-pair bf16x4 epilogue.
// ---------------------------------------------------------------------------
__global__ __launch_bounds__(256, 2) void gemm_num(
    const bf16* __restrict__ QKVG, const bf16* __restrict__ kvTall,
    const float* __restrict__ ksum, const float* __restrict__ vsum,
    const float* __restrict__ lepe_w, const float* __restrict__ lepe_b,
    bf16* __restrict__ obuf)
{
  __shared__ __align__(16) char smem[17408];
  bf16* As = (bf16*)smem;
  bf16* Bs = (bf16*)(smem + 8192);
  bf16* T  = (bf16*)smem;                      // epilogue, 64 rows, stride 136
  __shared__ float sden[128], svsum[128], slb[128], sksum[128];
  __shared__ float slw[5][128];

  const int t = threadIdx.x;
  const int h = blockIdx.y, b = blockIdx.z;
  const int bh = b * 8 + h;
  const long m0 = (long)blockIdx.x * 128;
  const bf16* A  = QKVG + (long)b * 16777216 + m0 * 4096 + h * 128;
  const bf16* Bw = kvTall + (long)bh * 16384;

  if (t < 128) {
    sksum[t] = ksum[bh * 128 + t];
    svsum[t] = vsum[bh * 128 + t];
    slb[t]   = lepe_b[h * 128 + t];
#pragma unroll
    for (int j = 0; j < 5; ++j) slw[j][t] = lepe_w[(h * 128 + t) * 5 + j];
  }

  const int i0 = t, i1 = t + 256;
  const bf16* gA0 = A + (long)(i0 >> 2) * 4096 + (i0 & 3) * 8;
  const bf16* gA1 = A + (long)(i1 >> 2) * 4096 + (i1 & 3) * 8;
  const bf16* gB0 = Bw + (long)(i0 >> 2) * 128 + (i0 & 3) * 8;
  const bf16* gB1 = Bw + (long)(i1 >> 2) * 128 + (i1 & 3) * 8;
  bf16* lA0 = As + i0 * 8; bf16* lA1 = As + i1 * 8;
  bf16* lB0 = Bs + i0 * 8; bf16* lB1 = Bs + i1 * 8;

  const int lane = t & 63, wv = t >> 6;
  const int moff = (wv & 1) * 64, noff = (wv >> 1) * 64;
  const int fm = lane & 15, fq = lane >> 4;

  f32x4 acc[4][4] = {};
  float dacc = 0.f;

  for (int k0 = 0; k0 < 128; k0 += 32) {
    async_copy16(gA0, lA0); async_copy16(gA1, lA1);
    async_copy16(gB0, lB0); async_copy16(gB1, lB1);
    gA0 += 32; gA1 += 32; gB0 += 32; gB1 += 32;
    __syncthreads();
    bf16x8 af[4], bfv[4];
#pragma unroll
    for (int i = 0; i < 4; ++i) {
      af[i]  = *(const bf16x8*)(As + (moff + i * 16 + fm) * 32 + fq * 8);
      bfv[i] = *(const bf16x8*)(Bs + (noff + i * 16 + fm) * 32 + fq * 8);
    }
#pragma unroll
    for (int i = 0; i < 4; ++i)
#pragma unroll
      for (int j = 0; j < 4; ++j)
        acc[i][j] = __builtin_amdgcn_mfma_f32_16x16x32_bf16(af[i], bfv[j], acc[i][j], 0, 0, 0);
    if (t < 128) {                 // den partial: row t, k-chunk k0..k0+32
#pragma unroll
      for (int c8 = 0; c8 < 4; ++c8) {
        bf16x8 q8 = *(const bf16x8*)(As + t * 32 + c8 * 8);
#pragma unroll
        for (int e = 0; e < 8; ++e) dacc += (float)q8[e] * sksum[k0 + c8 * 8 + e];
      }
    }
    __syncthreads();
  }
  if (t < 128) sden[t] = dacc * kScale + 4096.0f;

  // row-pair epilogue: lanes 0-31 -> even row cols 0..127 (4/lane),
  // lanes 32-63 -> odd row.
  const int lane32 = lane & 31, rsel = lane >> 5, c4 = lane32 * 4;
  float wj[5][4], lbv[4];
#pragma unroll
  for (int j = 0; j < 5; ++j)
#pragma unroll
    for (int cc = 0; cc < 4; ++cc) wj[j][cc] = slw[j][c4 + cc];
#pragma unroll
  for (int cc = 0; cc < 4; ++cc) lbv[cc] = slb[c4 + cc];

#pragma unroll
  for (int half = 0; half < 2; ++half) {
    if ((wv & 1) == half) {
#pragma unroll
      for (int i = 0; i < 4; ++i)
#pragma unroll
        for (int j = 0; j < 4; ++j)
#pragma unroll
          for (int r = 0; r < 4; ++r) {
            const int col = noff + j * 16 + fm;
            T[(i * 16 + fq * 4 + r) * 136 + col] = (bf16)(acc[i][j][r] * kScale + svsum[col]);
          }
    }
    __syncthreads();   // covers T (and sden on first pass)
    for (int rr = 0; rr < 8; ++rr) {
      const int lrow = wv * 16 + rr * 2 + rsel;  // 0..63
      const int row = half * 64 + lrow;          // 0..127 within tile
      const int s = (int)(m0 + row);
      const long grow = (long)b * 4096 + s;
      const float rden = 1.0f / sden[row];
      const bf16* vrow = QKVG + grow * 4096 + 2048 + h * 128 + c4;
      bf16x4 a4v = *(const bf16x4*)(T + lrow * 136 + c4);
      float lep[4] = {lbv[0], lbv[1], lbv[2], lbv[3]};
#pragma unroll
      for (int jt = 0; jt < 5; ++jt) {
        const int srow = s + jt - 2;
        if (srow >= 0 && srow < 4096) {
          bf16x4 v4 = *(const bf16x4*)(vrow + (long)(jt - 2) * 4096);
#pragma unroll
          for (int cc = 0; cc < 4; ++cc) lep[cc] += (float)v4[cc] * wj[jt][cc];
        }
      }
      bf16x4 g4 = *(const bf16x4*)(QKVG + grow * 4096 + 3072 + h * 128 + c4);
      bf16x4 o4;
#pragma unroll
      for (int cc = 0; cc < 4; ++cc)
        o4[cc] = (bf16)(((float)a4v[cc] * rden + lep[cc]) * (float)g4[cc]);
      *(bf16x4*)(obuf + grow * 1024 + h * 128 + c4) = o4;
    }
    __syncthreads();
  }
}

// ---------------------------------------------------------------------------
// prep: cast X->bf16, cast/concat weights, build rope sin/cos table.
// ---------------------------------------------------------------------------
__global__ void prep_kernel(const float* __restrict__ X, const float* __restrict__ Wq,
                            const float* __restrict__ Wk, const float* __restrict__ Wv,
                            const float* __restrict__ Wg, const float* __restrict__ Wo,
                            bf16* __restrict__ Xb, bf16* __restrict__ Wcat,
                            bf16* __restrict__ Wob, float2* __restrict__ tab)
{
  const int blk = blockIdx.x;
  if (blk < 16384) {
    long g = ((long)blk * 256 + threadIdx.x) * 4;
    float4 v = *(const float4*)(X + g);
    bf16x4 o = {(bf16)v.x, (bf16)v.y, (bf16)v.z, (bf16)v.w};
    *(bf16x4*)(Xb + g) = o;
  } else if (blk < 21504) {
    long g = ((long)(blk - 16384) * 256 + threadIdx.x) * 4;
    if (g < 4194304) {
      long idx = g & 1048575;
      int sel = (int)(g >> 20);
      const float* s = sel == 0 ? Wq : sel == 1 ? Wk : sel == 2 ? Wv : Wg;
      float4 v = *(const float4*)(s + idx);
      bf16x4 o = {(bf16)v.x, (bf16)v.y, (bf16)v.z, (bf16)v.w};
      *(bf16x4*)(Wcat + g) = o;
    } else {
      long idx = g - 4194304;
      float4 v = *(const float4*)(Wo + idx);
      bf16x4 o = {(bf16)v.x, (bf16)v.y, (bf16)v.z, (bf16)v.w};
      *(bf16x4*)(Wob + idx) = o;
    }
  } else {
    int idx = (blk - 21504) * 256 + threadIdx.x;
    int s = idx >> 6, i = idx & 63;
    float inv = powf(10000.0f, -((float)(2 * i)) / 128.0f);
    float ang = (float)s * inv;
    float sn, cs;
    sincosf(ang, &sn, &cs);
    tab[idx] = make_float2(sn, cs);
  }
}

// ---------------------------------------------------------------------------
// kv via MFMA with in-LDS transpose. Grid (16, 32) = 512 blocks (2/CU).
// kvp[chunk][bh][e][d] = sum_s v[s][e] k[s][d]; + ksum/vsum partials.
// ---------------------------------------------------------------------------
__global__ __launch_bounds__(256, 2) void kv_mfma(
    const bf16* __restrict__ QKVG, float* __restrict__ kvp,
    float* __restrict__ ksump, float* __restrict__ vsump)
{
  __shared__ __align__(16) bf16 VT[128 * 40];
  __shared__ __align__(16) bf16 KT[128 * 40];
  const int t = threadIdx.x;
  const int chunk = blockIdx.x, bh = blockIdx.y;
  const int b = bh >> 3, h = bh & 7;
  const long rowbase = ((long)b * 4096 + chunk * 256) * 4096 + h * 128;
  const bf16* Kg = QKVG + rowbase + 1024;
  const bf16* Vg = QKVG + rowbase + 2048;

  const int sp = t >> 4, fc = t & 15;
  const int lane = t & 63, wv = t >> 6;
  const int eoff = (wv & 1) * 64, doff = (wv >> 1) * 64;
  const int fm = lane & 15, fq = lane >> 4;
  const int srow = t & 127;
  const bool sumK = t >= 128;

  f32x4 acc[4][4] = {};
  float rsum = 0.f;

  for (int sb = 0; sb < 256; sb += 32) {
    const long go = (long)(sb + 2 * sp) * 4096 + fc * 8;
    bf16x8 v0 = *(const bf16x8*)(Vg + go);
    bf16x8 v1 = *(const bf16x8*)(Vg + go + 4096);
    bf16x8 k0 = *(const bf16x8*)(Kg + go);
    bf16x8 k1 = *(const bf16x8*)(Kg + go + 4096);
#pragma unroll
    for (int j = 0; j < 8; ++j) {
      const int f = fc * 8 + j;
      bf16x2 vp2 = {v0[j], v1[j]};
      bf16x2 kp2 = {k0[j], k1[j]};
      *(bf16x2*)(VT + f * 40 + 2 * sp) = vp2;
      *(bf16x2*)(KT + f * 40 + 2 * sp) = kp2;
    }
    __syncthreads();
    bf16x8 af[4], bfv[4];
#pragma unroll
    for (int i = 0; i < 4; ++i) {
      af[i]  = *(const bf16x8*)(VT + (eoff + i * 16 + fm) * 40 + fq * 8);
      bfv[i] = *(const bf16x8*)(KT + (doff + i * 16 + fm) * 40 + fq * 8);
    }
#pragma unroll
    for (int i = 0; i < 4; ++i)
#pragma unroll
      for (int j = 0; j < 4; ++j)
        acc[i][j] = __builtin_amdgcn_mfma_f32_16x16x32_bf16(af[i], bfv[j], acc[i][j], 0, 0, 0);
    const bf16* rp = (sumK ? KT : VT) + srow * 40;
#pragma unroll
    for (int i = 0; i < 4; ++i) {
      bf16x8 r8 = *(const bf16x8*)(rp + i * 8);
#pragma unroll
      for (int j = 0; j < 8; ++j) rsum += (float)r8[j];
    }
    __syncthreads();
  }

  float* plane = kvp + ((long)chunk * 32 + bh) * 16384;
#pragma unroll
  for (int i = 0; i < 4; ++i)
#pragma unroll
    for (int j = 0; j < 4; ++j)
#pragma unroll
      for (int r = 0; r < 4; ++r)
        plane[(long)(eoff + i * 16 + fq * 4 + r) * 128 + (doff + j * 16 + fm)] = acc[i][j][r];
  float* sdst = (sumK ? ksump : vsump) + ((long)chunk * 32 + bh) * 128 + srow;
  *sdst = rsum;
}

// Fold 16 chunk partials -> bf16 kvT + f32 ksum/vsum.
__global__ void kv_reduce(const float* __restrict__ kvp, const float* __restrict__ ksump,
                          const float* __restrict__ vsump, bf16* __restrict__ kvT,
                          float* __restrict__ ksum, float* __restrict__ vsum)
{
  long g = (long)blockIdx.x * 256 + threadIdx.x;
  long bh = g >> 14, idx = g & 16383;
  float s = 0.f;
#pragma unroll
  for (int c = 0; c < 16; ++c) s += kvp[((long)c * 32 + bh) * 16384 + idx];
  kvT[g] = (bf16)s;
  if (g < 8192) {
    int bh2 = (int)(g >> 8), rem = (int)(g & 255), f = rem & 127;
    const float* src = (rem >> 7) ? ksump : vsump;
    float* dst = (rem >> 7) ? ksum : vsum;
    float s2 = 0.f;
#pragma unroll
    for (int c = 0; c < 16; ++c) s2 += src[((long)c * 32 + bh2) * 128 + f];
    dst[bh2 * 128 + f] = s2;
  }
}

// ---------------------------------------------------------------------------
extern "C" void kernel_launch(void* const* d_in, const int* in_sizes, int n_in,
                              void* d_out, int out_size, void* d_ws, size_t ws_size,
                              hipStream_t stream)
{
  const float* X      = (const float*)d_in[0];
  const float* Wq     = (const float*)d_in[1];
  const float* Wk     = (const float*)d_in[2];
  const float* Wv     = (const float*)d_in[3];
  const float* Wg     = (const float*)d_in[4];
  const float* Wo     = (const float*)d_in[5];
  const float* lepe_w = (const float*)d_in[6];
  const float* lepe_b = (const float*)d_in[7];
  float* out = (float*)d_out;

  char* ws = (char*)d_ws;
  bf16*   Xb    = (bf16*)(ws);
  float*  kvp   = (float*)(ws);                  // aliases Xb (dead after proj)
  bf16*   Wcat  = (bf16*)(ws + 33554432);
  bf16*   Wob   = (bf16*)(ws + 41943040);
  float2* tab   = (float2*)(ws + 44040192);
  float*  ksump = (float*)(ws + 44040192);       // aliases tab (dead after proj)
  float*  vsump = (float*)(ws + 44302336);
  bf16*   QKVG  = (bf16*)(ws + 46137344);
  float*  ksum  = (float*)(ws + 180355072);
  float*  vsum  = (float*)(ws + 180371456);
  bf16*   kvT   = (bf16*)(ws + 180387840);
  bf16*   obuf  = (bf16*)(ws + 181960704);

  prep_kernel<<<22528, 256, 0, stream>>>(X, Wq, Wk, Wv, Wg, Wo, Xb, Wcat, Wob, tab);

  gemm_qkvg<<<1024, 512, 0, stream>>>(Xb, Wcat, QKVG, tab);

  kv_mfma<<<dim3(16, 32), 256, 0, stream>>>(QKVG, kvp, ksump, vsump);
  kv_reduce<<<2048, 256, 0, stream>>>(kvp, ksump, vsump, kvT, ksum, vsum);

  gemm_num<<<dim3(32, 8, 4), 256, 0, stream>>>(QKVG, kvT, ksum, vsum, lepe_w, lepe_b, obuf);

  gemm_final<<<1024, 256, 0, stream>>>(obuf, Wob, out);
}

// Round 8
// 393.030 us; speedup vs baseline: 2.4555x; 2.4555x over previous
//
#include <hip/hip_runtime.h>
#include <math.h>
#include <stdint.h>

// ---------------------------------------------------------------------------
// MalaAttention on MI355X (gfx950). Round 13:
//  - gemm_final: FIX rule-#20 scratch spill from round 12 — the epilogue
//    p-loop was "#pragma unroll 1", making acc[ib+i2] a runtime index ->
//    whole accumulator in scratch (VGPR 56, WRITE 2.1GB, MfmaUtil 2%).
//    Now fully unrolled: ib compile-time, acc stays in VGPRs.
//  - everything else identical to round 12 (qkvg round-8 schedule,
//    gemm_num row-pair bf16x4 epilogue).
//
// Workspace layout (bytes):
//   Xb    @ 0          32MB  bf16 X        (dead after proj -> kvp)
//   kvp   @ 0          32MB  f32 [16][bh][128][128] kv partials
//   Wcat  @ 33554432    8MB  bf16 [Wq;Wk;Wv;Wg]
//   Wob   @ 41943040    2MB  bf16 Wo
//   tab   @ 44040192    2MB  float2 [4096][64] rope sin/cos (dead after proj)
//   ksump @ 44040192  256KB  f32 [16][bh][128]   (aliases tab)
//   vsump @ 44302336  256KB  f32 [16][bh][128]
//   QKVG  @ 46137344  128MB  bf16 [16384][4096] col blocks: q|k|v|g
//   ksum  @ 180355072  16KB  f32 [bh][128]
//   vsum  @ 180371456  16KB  f32 [bh][128]
//   kvT   @ 180387840   1MB  bf16 kvT[bh][e][d]
//   obuf  @ 181960704  32MB  bf16 gated out
// ---------------------------------------------------------------------------

typedef __bf16 bf16;
typedef __bf16 bf16x2 __attribute__((ext_vector_type(2)));
typedef __bf16 bf16x4 __attribute__((ext_vector_type(4)));
typedef __bf16 bf16x8 __attribute__((ext_vector_type(8)));
typedef float f32x4 __attribute__((ext_vector_type(4)));

static constexpr float kScale = 0.08838834764831845f; // 1/sqrt(128)

__device__ __forceinline__ void async_copy16(const void* g, void* l) {
  __builtin_amdgcn_global_load_lds(
      (const __attribute__((address_space(1))) void*)(uintptr_t)g,
      (__attribute__((address_space(3))) void*)(uintptr_t)l, 16, 0, 0);
}

// ---------------------------------------------------------------------------
// Proj GEMM: QKVG = Xb @ Wcat^T. 256x256 tile, BK=64, 8-phase schedule.
// Grid 1024 (64 m-tiles x 16 n-tiles), XCD m-partitioned. RoPE fused (by<8).
// ---------------------------------------------------------------------------
__global__ __launch_bounds__(512, 1) void gemm_qkvg(
    const bf16* __restrict__ A, const bf16* __restrict__ Bw,
    bf16* __restrict__ C, const float2* __restrict__ tab)
{
  __shared__ __align__(16) char smem[131072];

  const int t = threadIdx.x;
  const int bid = blockIdx.x;
  const int n = bid >> 3;
  const int bx = (bid & 7) * 8 + (n & 7);         // 8 m-tiles per XCD
  const int by = n >> 3;                          // 0..15
  const long m0 = (long)bx * 256;
  const long n0 = (long)by * 256;

  const int d0 = t * 16;
  const int dd = d0 ^ (((d0 >> 7) & 7) << 4);
  const int rT = dd >> 7;
  const int cT = (dd & 127) >> 1;
  const bf16* aSt = A  + (m0 + rT) * 1024 + cT;
  const bf16* bSt = Bw + (n0 + rT) * 1024 + cT;
  char* ldsDst = smem + d0;

  const int lane = t & 63, wid = t >> 6;
  const int wm = wid >> 2, wn = wid & 3;
  const int fm = lane & 15, fq = lane >> 4;
  const int xsw = (fm & 7) << 4;
  const int o0 = (fq * 16) ^ xsw;
  const int o1 = o0 ^ 64;
  const char* ldsA0 = smem + wm * 16384 + fm * 128 + o0;
  const char* ldsA1 = smem + wm * 16384 + fm * 128 + o1;
  const char* ldsB0 = smem + 32768 + (wn >> 1) * 16384 +
                      ((wn & 1) * 64 + fm) * 128 + o0;
  const char* ldsB1 = ldsB0 + (o1 - o0);

  f32x4 acc[8][4] = {};
  bf16x8 a4[4][2], b4[4][2];

#define STAGE_A(kt, h) do {                                                  \
    const bf16* s_ = aSt + (long)(h) * 131072 + (kt) * 64;                   \
    char* d_ = ldsDst + ((kt) & 1) * 65536 + (h) * 16384;                    \
    async_copy16(s_, d_);                                                    \
    async_copy16(s_ + 65536, d_ + 8192);                                     \
  } while (0)
#define STAGE_B(kt, h) do {                                                  \
    const bf16* s_ = bSt + (long)(h) * 131072 + (kt) * 64;                   \
    char* d_ = ldsDst + ((kt) & 1) * 65536 + 32768 + (h) * 16384;            \
    async_copy16(s_, d_);                                                    \
    async_copy16(s_ + 65536, d_ + 8192);                                     \
  } while (0)
#define LOAD_A(buf, qi) do {                                                 \
    const char* p0_ = ldsA0 + (buf) * 65536 + (qi) * 8192;                   \
    const char* p1_ = ldsA1 + (buf) * 65536 + (qi) * 8192;                   \
    a4[0][0] = *(const bf16x8*)(p0_);                                        \
    a4[0][1] = *(const bf16x8*)(p1_);                                        \
    a4[1][0] = *(const bf16x8*)(p0_ + 2048);                                 \
    a4[1][1] = *(const bf16x8*)(p1_ + 2048);                                 \
    a4[2][0] = *(const bf16x8*)(p0_ + 4096);                                 \
    a4[2][1] = *(const bf16x8*)(p1_ + 4096);                                 \
    a4[3][0] = *(const bf16x8*)(p0_ + 6144);                                 \
    a4[3][1] = *(const bf16x8*)(p1_ + 6144);                                 \
  } while (0)
#define LOAD_B(buf, qj) do {                                                 \
    const char* p0_ = ldsB0 + (buf) * 65536 + (qj) * 4096;                   \
    const char* p1_ = ldsB1 + (buf) * 65536 + (qj) * 4096;                   \
    b4[2*(qj)+0][0] = *(const bf16x8*)(p0_);                                 \
    b4[2*(qj)+0][1] = *(const bf16x8*)(p1_);                                 \
    b4[2*(qj)+1][0] = *(const bf16x8*)(p0_ + 2048);                          \
    b4[2*(qj)+1][1] = *(const bf16x8*)(p1_ + 2048);                          \
  } while (0)
#define MM1(i, j, ks)                                                        \
    acc[i][j] = __builtin_amdgcn_mfma_f32_16x16x32_bf16(                     \
        a4[(i) & 3][ks], b4[j][ks], acc[i][j], 0, 0, 0)
#define MFMA_Q(qi, qj) do {                                                  \
    MM1(4*(qi)+0, 2*(qj)+0, 0); MM1(4*(qi)+1, 2*(qj)+0, 0);                  \
    MM1(4*(qi)+2, 2*(qj)+0, 0); MM1(4*(qi)+3, 2*(qj)+0, 0);                  \
    MM1(4*(qi)+0, 2*(qj)+1, 0); MM1(4*(qi)+1, 2*(qj)+1, 0);                  \
    MM1(4*(qi)+2, 2*(qj)+1, 0); MM1(4*(qi)+3, 2*(qj)+1, 0);                  \
    MM1(4*(qi)+0, 2*(qj)+0, 1); MM1(4*(qi)+1, 2*(qj)+0, 1);                  \
    MM1(4*(qi)+2, 2*(qj)+0, 1); MM1(4*(qi)+3, 2*(qj)+0, 1);                  \
    MM1(4*(qi)+0, 2*(qj)+1, 1); MM1(4*(qi)+1, 2*(qj)+1, 1);                  \
    MM1(4*(qi)+2, 2*(qj)+1, 1); MM1(4*(qi)+3, 2*(qj)+1, 1);                  \
  } while (0)
#define BAR()    __builtin_amdgcn_s_barrier()
#define SCHEDB() __builtin_amdgcn_sched_barrier(0)
#define PRIO(p)  __builtin_amdgcn_s_setprio(p)

  STAGE_A(0, 0); STAGE_A(0, 1); STAGE_B(0, 0); STAGE_B(0, 1);
  STAGE_A(1, 0);
  asm volatile("s_waitcnt vmcnt(2)" ::: "memory");
  BAR(); SCHEDB();

#pragma unroll 1
  for (int it = 0; it < 7; ++it) {
    const int k1 = 2 * it + 1;
    const int k2 = 2 * it + 2;
    const int k3 = 2 * it + 3;
    LOAD_A(0, 0); LOAD_B(0, 0);
    STAGE_A(k1, 1);
    BAR(); SCHEDB(); PRIO(1); MFMA_Q(0, 0); PRIO(0); BAR(); SCHEDB();
    LOAD_B(0, 1);
    STAGE_B(k1, 0);
    BAR(); SCHEDB(); PRIO(1); MFMA_Q(0, 1); PRIO(0); BAR(); SCHEDB();
    LOAD_A(0, 1);
    STAGE_B(k1, 1);
    BAR(); SCHEDB(); PRIO(1); MFMA_Q(1, 1); PRIO(0); BAR(); SCHEDB();
    STAGE_A(k2, 0);
    BAR(); SCHEDB(); PRIO(1); MFMA_Q(1, 0); PRIO(0);
    asm volatile("s_waitcnt vmcnt(2)" ::: "memory");
    BAR(); SCHEDB();
    LOAD_A(1, 0); LOAD_B(1, 0);
    STAGE_A(k2, 1);
    BAR(); SCHEDB(); PRIO(1); MFMA_Q(0, 0); PRIO(0); BAR(); SCHEDB();
    LOAD_B(1, 1);
    STAGE_B(k2, 0);
    BAR(); SCHEDB(); PRIO(1); MFMA_Q(0, 1); PRIO(0); BAR(); SCHEDB();
    LOAD_A(1, 1);
    STAGE_B(k2, 1);
    BAR(); SCHEDB(); PRIO(1); MFMA_Q(1, 1); PRIO(0); BAR(); SCHEDB();
    STAGE_A(k3, 0);
    BAR(); SCHEDB(); PRIO(1); MFMA_Q(1, 0); PRIO(0);
    asm volatile("s_waitcnt vmcnt(2)" ::: "memory");
    BAR(); SCHEDB();
  }

  {
    LOAD_A(0, 0); LOAD_B(0, 0);
    STAGE_A(15, 1);
    BAR(); SCHEDB(); PRIO(1); MFMA_Q(0, 0); PRIO(0); BAR(); SCHEDB();
    LOAD_B(0, 1);
    STAGE_B(15, 0);
    BAR(); SCHEDB(); PRIO(1); MFMA_Q(0, 1); PRIO(0); BAR(); SCHEDB();
    LOAD_A(0, 1);
    STAGE_B(15, 1);
    BAR(); SCHEDB(); PRIO(1); MFMA_Q(1, 1); PRIO(0); BAR(); SCHEDB();
    BAR(); SCHEDB(); PRIO(1); MFMA_Q(1, 0); PRIO(0);
    asm volatile("s_waitcnt vmcnt(0)" ::: "memory");
    BAR(); SCHEDB();
    LOAD_A(1, 0); LOAD_B(1, 0);
    BAR(); SCHEDB(); PRIO(1); MFMA_Q(0, 0); PRIO(0); BAR(); SCHEDB();
    LOAD_B(1, 1);
    BAR(); SCHEDB(); PRIO(1); MFMA_Q(0, 1); PRIO(0); BAR(); SCHEDB();
    LOAD_A(1, 1);
    BAR(); SCHEDB(); PRIO(1); MFMA_Q(1, 1); PRIO(0); BAR(); SCHEDB();
    BAR(); SCHEDB(); PRIO(1); MFMA_Q(1, 0); PRIO(0); BAR(); SCHEDB();
  }

#undef STAGE_A
#undef STAGE_B
#undef LOAD_A
#undef LOAD_B
#undef MM1
#undef MFMA_Q
#undef BAR
#undef SCHEDB
#undef PRIO

  // ---- epilogue: two 128-row half-passes through T[128][264] (RoPE by<8)
  bf16* T = (bf16*)smem;
  __syncthreads();
#pragma unroll 1
  for (int hw = 0; hw < 2; ++hw) {
    if (wm == hw) {
#pragma unroll
      for (int rf = 0; rf < 8; ++rf)
#pragma unroll
        for (int cf = 0; cf < 4; ++cf)
#pragma unroll
          for (int r = 0; r < 4; ++r)
            T[(rf * 16 + fq * 4 + r) * 264 + wn * 64 + cf * 16 + fm] =
                (bf16)acc[rf][cf][r];
    }
    __syncthreads();
    if (by < 8) {  // q|k region: RoPE pair rotation in LDS
#pragma unroll
      for (int ii = 0; ii < 32; ++ii) {
        const int pi = t + ii * 512;            // 16384 pairs
        const int row = pi >> 7, pr = pi & 127;
        const int hd = pr >> 6, i = pr & 63;
        const int c0 = hd * 128 + i;
        const int s = (int)((m0 + hw * 128 + row) & 4095);
        const float2 sc = tab[s * 64 + i];
        float x1 = (float)T[row * 264 + c0];
        float x2 = (float)T[row * 264 + c0 + 64];
        T[row * 264 + c0]      = (bf16)(x1 * sc.y - x2 * sc.x);
        T[row * 264 + c0 + 64] = (bf16)(x2 * sc.y + x1 * sc.x);
      }
      __syncthreads();
    }
#pragma unroll
    for (int ii = 0; ii < 8; ++ii) {
      const int cid = t + ii * 512;
      const int row = cid >> 5, ch = cid & 31;
      *(bf16x8*)(C + (m0 + hw * 128 + row) * 4096 + n0 + ch * 8) =
          *(const bf16x8*)(T + row * 264 + ch * 8);
    }
    __syncthreads();
  }
}

// ---------------------------------------------------------------------------
// Final NT GEMM: out = obuf @ Wo^T, fp32 out. 128x128 tile, 1D grid 1024,
// XCD-swizzled, 2 blocks/CU. Coalesced store via float T2[32][132] LDS.
// Epilogue p-loop FULLY UNROLLED (rule #20: acc index must be compile-time).
// ---------------------------------------------------------------------------
__global__ __launch_bounds__(256, 2) void gemm_final(
    const bf16* __restrict__ A, const bf16* __restrict__ Bw,
    float* __restrict__ C)
{
  __shared__ __align__(16) char smem[17408];
  bf16* As = (bf16*)smem;
  bf16* Bs = (bf16*)(smem + 8192);
  const int t = threadIdx.x;
  const int bid = blockIdx.x;
  const int xcd = bid & 7, n = bid >> 3;
  const int bx = xcd * 16 + (n & 15);
  const int by = n >> 4;
  const long m0 = (long)bx * 128;
  A  += m0 * 1024;
  Bw += (long)by * 131072;
  C  += m0 * 1024 + (long)by * 128;

  const int i0 = t, i1 = t + 256;
  const bf16* gA0 = A  + (long)(i0 >> 2) * 1024 + (i0 & 3) * 8;
  const bf16* gA1 = A  + (long)(i1 >> 2) * 1024 + (i1 & 3) * 8;
  const bf16* gB0 = Bw + (long)(i0 >> 2) * 1024 + (i0 & 3) * 8;
  const bf16* gB1 = Bw + (long)(i1 >> 2) * 1024 + (i1 & 3) * 8;
  bf16* lA0 = As + i0 * 8; bf16* lA1 = As + i1 * 8;
  bf16* lB0 = Bs + i0 * 8; bf16* lB1 = Bs + i1 * 8;

  const int lane = t & 63, wv = t >> 6;
  const int moff = (wv & 1) * 64, noff = (wv >> 1) * 64;
  const int fm = lane & 15, fq = lane >> 4;

  f32x4 acc[4][4] = {};

  for (int k0 = 0; k0 < 1024; k0 += 32) {
    async_copy16(gA0, lA0); async_copy16(gA1, lA1);
    async_copy16(gB0, lB0); async_copy16(gB1, lB1);
    gA0 += 32; gA1 += 32; gB0 += 32; gB1 += 32;
    __syncthreads();
    bf16x8 af[4], bfv[4];
#pragma unroll
    for (int i = 0; i < 4; ++i) {
      af[i]  = *(const bf16x8*)(As + (moff + i * 16 + fm) * 32 + fq * 8);
      bfv[i] = *(const bf16x8*)(Bs + (noff + i * 16 + fm) * 32 + fq * 8);
    }
#pragma unroll
    for (int i = 0; i < 4; ++i)
#pragma unroll
      for (int j = 0; j < 4; ++j)
        acc[i][j] = __builtin_amdgcn_mfma_f32_16x16x32_bf16(af[i], bfv[j], acc[i][j], 0, 0, 0);
    __syncthreads();
  }

  // ---- coalesced store: 4 quarter-passes (32 rows) through T2[32][132].
  // FULL unroll: all acc indices compile-time constants (rule #20).
  float* T2 = (float*)smem;
#pragma unroll
  for (int p = 0; p < 4; ++p) {
    if ((wv & 1) == (p >> 1)) {   // waves whose moff matches this quarter
      const int ib = (p & 1) * 2;
#pragma unroll
      for (int i2 = 0; i2 < 2; ++i2)
#pragma unroll
        for (int j = 0; j < 4; ++j)
#pragma unroll
          for (int r = 0; r < 4; ++r)
            T2[(i2 * 16 + fq * 4 + r) * 132 + noff + j * 16 + fm] =
                acc[ib + i2][j][r];
    }
    __syncthreads();
#pragma unroll
    for (int ii = 0; ii < 4; ++ii) {
      const int cid = t + ii * 256;           // 1024 float4 chunks
      const int row = cid >> 5, ch = cid & 31;
      *(float4*)(C + (long)(p * 32 + row) * 1024 + ch * 4) =
          *(const float4*)(T2 + row * 132 + ch * 4);
    }
    __syncthreads();
  }
}

// ---------------------------------------------------------------------------
// num GEMM (per b,h: M=4096 N=128 K=128) + fused den + mala/LePE/gate.
// Half-tile epilogue (T = 64x136); row-pair bf16x4 epilogue.
// ---------------------------------------------------------------------------
__global__ __launch_bounds__(256, 2) void gemm_num(
    const bf16* __restrict__ QKVG, const bf16* __restrict__ kvTall,
    const float* __restrict__ ksum, const float* __restrict__ vsum,
    const float* __restrict__ lepe_w, const float* __restrict__ lepe_b,
    bf16* __restrict__ obuf)
{
  __shared__ __align__(16) char smem[17408];
  bf16* As = (bf16*)smem;
  bf16* Bs = (bf16*)(smem + 8192);
  bf16* T  = (bf16*)smem;                      // epilogue, 64 rows, stride 136
  __shared__ float sden[128], svsum[128], slb[128], sksum[128];
  __shared__ float slw[5][128];

  const int t = threadIdx.x;
  const int h = blockIdx.y, b = blockIdx.z;
  const int bh = b * 8 + h;
  const long m0 = (long)blockIdx.x * 128;
  const bf16* A  = QKVG + (long)b * 16777216 + m0 * 4096 + h * 128;
  const bf16* Bw = kvTall + (long)bh * 16384;

  if (t < 128) {
    sksum[t] = ksum[bh * 128 + t];
    svsum[t] = vsum[bh * 128 + t];
    slb[t]   = lepe_b[h * 128 + t];
#pragma unroll
    for (int j = 0; j < 5; ++j) slw[j][t] = lepe_w[(h * 128 + t) * 5 + j];
  }

  const int i0 = t, i1 = t + 256;
  const bf16* gA0 = A + (long)(i0 >> 2) * 4096 + (i0 & 3) * 8;
  const bf16* gA1 = A + (long)(i1 >> 2) * 4096 + (i1 & 3) * 8;
  const bf16* gB0 = Bw + (long)(i0 >> 2) * 128 + (i0 & 3) * 8;
  const bf16* gB1 = Bw + (long)(i1 >> 2) * 128 + (i1 & 3) * 8;
  bf16* lA0 = As + i0 * 8; bf16* lA1 = As + i1 * 8;
  bf16* lB0 = Bs + i0 * 8; bf16* lB1 = Bs + i1 * 8;

  const int lane = t & 63, wv = t >> 6;
  const int moff = (wv & 1) * 64, noff = (wv >> 1) * 64;
  const int fm = lane & 15, fq = lane >> 4;

  f32x4 acc[4][4] = {};
  float dacc = 0.f;

  for (int k0 = 0; k0 < 128; k0 += 32) {
    async_copy16(gA0, lA0); async_copy16(gA1, lA1);
    async_copy16(gB0, lB0); async_copy16(gB1, lB1);
    gA0 += 32; gA1 += 32; gB0 += 32; gB1 += 32;
    __syncthreads();
    bf16x8 af[4], bfv[4];
#pragma unroll
    for (int i = 0; i < 4; ++i) {
      af[i]  = *(const bf16x8*)(As + (moff + i * 16 + fm) * 32 + fq * 8);
      bfv[i] = *(const bf16x8*)(Bs + (noff + i * 16 + fm) * 32 + fq * 8);
    }
#pragma unroll
    for (int i = 0; i < 4; ++i)
#pragma unroll
      for (int j = 0; j < 4; ++j)
        acc[i][j] = __builtin_amdgcn_mfma_f32_16x16x32_bf16(af[i], bfv[j], acc[i][j], 0, 0, 0);
    if (t < 128) {                 // den partial: row t, k-chunk k0..k0+32
#pragma unroll
      for (int c8 = 0; c8 < 4; ++c8) {
        bf16x8 q8 = *(const bf16x8*)(As + t * 32 + c8 * 8);
#pragma unroll
        for (int e = 0; e < 8; ++e) dacc += (float)q8[e] * sksum[k0 + c8 * 8 + e];
      }
    }
    __syncthreads();
  }
  if (t < 128) sden[t] = dacc * kScale + 4096.0f;

  // row-pair epilogue: lanes 0-31 -> even row cols 0..127 (4/lane),
  // lanes 32-63 -> odd row.
  const int lane32 = lane & 31, rsel = lane >> 5, c4 = lane32 * 4;
  float wj[5][4], lbv[4];
#pragma unroll
  for (int j = 0; j < 5; ++j)
#pragma unroll
    for (int cc = 0; cc < 4; ++cc) wj[j][cc] = slw[j][c4 + cc];
#pragma unroll
  for (int cc = 0; cc < 4; ++cc) lbv[cc] = slb[c4 + cc];

#pragma unroll
  for (int half = 0; half < 2; ++half) {
    if ((wv & 1) == half) {
#pragma unroll
      for (int i = 0; i < 4; ++i)
#pragma unroll
        for (int j = 0; j < 4; ++j)
#pragma unroll
          for (int r = 0; r < 4; ++r) {
            const int col = noff + j * 16 + fm;
            T[(i * 16 + fq * 4 + r) * 136 + col] = (bf16)(acc[i][j][r] * kScale + svsum[col]);
          }
    }
    __syncthreads();   // covers T (and sden on first pass)
    for (int rr = 0; rr < 8; ++rr) {
      const int lrow = wv * 16 + rr * 2 + rsel;  // 0..63
      const int row = half * 64 + lrow;          // 0..127 within tile
      const int s = (int)(m0 + row);
      const long grow = (long)b * 4096 + s;
      const float rden = 1.0f / sden[row];
      const bf16* vrow = QKVG + grow * 4096 + 2048 + h * 128 + c4;
      bf16x4 a4v = *(const bf16x4*)(T + lrow * 136 + c4);
      float lep[4] = {lbv[0], lbv[1], lbv[2], lbv[3]};
#pragma unroll
      for (int jt = 0; jt < 5; ++jt) {
        const int srow = s + jt - 2;
        if (srow >= 0 && srow < 4096) {
          bf16x4 v4 = *(const bf16x4*)(vrow + (long)(jt - 2) * 4096);
#pragma unroll
          for (int cc = 0; cc < 4; ++cc) lep[cc] += (float)v4[cc] * wj[jt][cc];
        }
      }
      bf16x4 g4 = *(const bf16x4*)(QKVG + grow * 4096 + 3072 + h * 128 + c4);
      bf16x4 o4;
#pragma unroll
      for (int cc = 0; cc < 4; ++cc)
        o4[cc] = (bf16)(((float)a4v[cc] * rden + lep[cc]) * (float)g4[cc]);
      *(bf16x4*)(obuf + grow * 1024 + h * 128 + c4) = o4;
    }
    __syncthreads();
  }
}

// ---------------------------------------------------------------------------
// prep: cast X->bf16, cast/concat weights, build rope sin/cos table.
// ---------------------------------------------------------------------------
__global__ void prep_kernel(const float* __restrict__ X, const float* __restrict__ Wq,
                            const float* __restrict__ Wk, const float* __restrict__ Wv,
                            const float* __restrict__ Wg, const float* __restrict__ Wo,
                            bf16* __restrict__ Xb, bf16* __restrict__ Wcat,
                            bf16* __restrict__ Wob, float2* __restrict__ tab)
{
  const int blk = blockIdx.x;
  if (blk < 16384) {
    long g = ((long)blk * 256 + threadIdx.x) * 4;
    float4 v = *(const float4*)(X + g);
    bf16x4 o = {(bf16)v.x, (bf16)v.y, (bf16)v.z, (bf16)v.w};
    *(bf16x4*)(Xb + g) = o;
  } else if (blk < 21504) {
    long g = ((long)(blk - 16384) * 256 + threadIdx.x) * 4;
    if (g < 4194304) {
      long idx = g & 1048575;
      int sel = (int)(g >> 20);
      const float* s = sel == 0 ? Wq : sel == 1 ? Wk : sel == 2 ? Wv : Wg;
      float4 v = *(const float4*)(s + idx);
      bf16x4 o = {(bf16)v.x, (bf16)v.y, (bf16)v.z, (bf16)v.w};
      *(bf16x4*)(Wcat + g) = o;
    } else {
      long idx = g - 4194304;
      float4 v = *(const float4*)(Wo + idx);
      bf16x4 o = {(bf16)v.x, (bf16)v.y, (bf16)v.z, (bf16)v.w};
      *(bf16x4*)(Wob + idx) = o;
    }
  } else {
    int idx = (blk - 21504) * 256 + threadIdx.x;
    int s = idx >> 6, i = idx & 63;
    float inv = powf(10000.0f, -((float)(2 * i)) / 128.0f);
    float ang = (float)s * inv;
    float sn, cs;
    sincosf(ang, &sn, &cs);
    tab[idx] = make_float2(sn, cs);
  }
}

// ---------------------------------------------------------------------------
// kv via MFMA with in-LDS transpose. Grid (16, 32) = 512 blocks (2/CU).
// kvp[chunk][bh][e][d] = sum_s v[s][e] k[s][d]; + ksum/vsum partials.
// ---------------------------------------------------------------------------
__global__ __launch_bounds__(256, 2) void kv_mfma(
    const bf16* __restrict__ QKVG, float* __restrict__ kvp,
    float* __restrict__ ksump, float* __restrict__ vsump)
{
  __shared__ __align__(16) bf16 VT[128 * 40];
  __shared__ __align__(16) bf16 KT[128 * 40];
  const int t = threadIdx.x;
  const int chunk = blockIdx.x, bh = blockIdx.y;
  const int b = bh >> 3, h = bh & 7;
  const long rowbase = ((long)b * 4096 + chunk * 256) * 4096 + h * 128;
  const bf16* Kg = QKVG + rowbase + 1024;
  const bf16* Vg = QKVG + rowbase + 2048;

  const int sp = t >> 4, fc = t & 15;
  const int lane = t & 63, wv = t >> 6;
  const int eoff = (wv & 1) * 64, doff = (wv >> 1) * 64;
  const int fm = lane & 15, fq = lane >> 4;
  const int srow = t & 127;
  const bool sumK = t >= 128;

  f32x4 acc[4][4] = {};
  float rsum = 0.f;

  for (int sb = 0; sb < 256; sb += 32) {
    const long go = (long)(sb + 2 * sp) * 4096 + fc * 8;
    bf16x8 v0 = *(const bf16x8*)(Vg + go);
    bf16x8 v1 = *(const bf16x8*)(Vg + go + 4096);
    bf16x8 k0 = *(const bf16x8*)(Kg + go);
    bf16x8 k1 = *(const bf16x8*)(Kg + go + 4096);
#pragma unroll
    for (int j = 0; j < 8; ++j) {
      const int f = fc * 8 + j;
      bf16x2 vp2 = {v0[j], v1[j]};
      bf16x2 kp2 = {k0[j], k1[j]};
      *(bf16x2*)(VT + f * 40 + 2 * sp) = vp2;
      *(bf16x2*)(KT + f * 40 + 2 * sp) = kp2;
    }
    __syncthreads();
    bf16x8 af[4], bfv[4];
#pragma unroll
    for (int i = 0; i < 4; ++i) {
      af[i]  = *(const bf16x8*)(VT + (eoff + i * 16 + fm) * 40 + fq * 8);
      bfv[i] = *(const bf16x8*)(KT + (doff + i * 16 + fm) * 40 + fq * 8);
    }
#pragma unroll
    for (int i = 0; i < 4; ++i)
#pragma unroll
      for (int j = 0; j < 4; ++j)
        acc[i][j] = __builtin_amdgcn_mfma_f32_16x16x32_bf16(af[i], bfv[j], acc[i][j], 0, 0, 0);
    const bf16* rp = (sumK ? KT : VT) + srow * 40;
#pragma unroll
    for (int i = 0; i < 4; ++i) {
      bf16x8 r8 = *(const bf16x8*)(rp + i * 8);
#pragma unroll
      for (int j = 0; j < 8; ++j) rsum += (float)r8[j];
    }
    __syncthreads();
  }

  float* plane = kvp + ((long)chunk * 32 + bh) * 16384;
#pragma unroll
  for (int i = 0; i < 4; ++i)
#pragma unroll
    for (int j = 0; j < 4; ++j)
#pragma unroll
      for (int r = 0; r < 4; ++r)
        plane[(long)(eoff + i * 16 + fq * 4 + r) * 128 + (doff + j * 16 + fm)] = acc[i][j][r];
  float* sdst = (sumK ? ksump : vsump) + ((long)chunk * 32 + bh) * 128 + srow;
  *sdst = rsum;
}

// Fold 16 chunk partials -> bf16 kvT + f32 ksum/vsum.
__global__ void kv_reduce(const float* __restrict__ kvp, const float* __restrict__ ksump,
                          const float* __restrict__ vsump, bf16* __restrict__ kvT,
                          float* __restrict__ ksum, float* __restrict__ vsum)
{
  long g = (long)blockIdx.x * 256 + threadIdx.x;
  long bh = g >> 14, idx = g & 16383;
  float s = 0.f;
#pragma unroll
  for (int c = 0; c < 16; ++c) s += kvp[((long)c * 32 + bh) * 16384 + idx];
  kvT[g] = (bf16)s;
  if (g < 8192) {
    int bh2 = (int)(g >> 8), rem = (int)(g & 255), f = rem & 127;
    const float* src = (rem >> 7) ? ksump : vsump;
    float* dst = (rem >> 7) ? ksum : vsum;
    float s2 = 0.f;
#pragma unroll
    for (int c = 0; c < 16; ++c) s2 += src[((long)c * 32 + bh2) * 128 + f];
    dst[bh2 * 128 + f] = s2;
  }
}

// ---------------------------------------------------------------------------
extern "C" void kernel_launch(void* const* d_in, const int* in_sizes, int n_in,
                              void* d_out, int out_size, void* d_ws, size_t ws_size,
                              hipStream_t stream)
{
  const float* X      = (const float*)d_in[0];
  const float* Wq     = (const float*)d_in[1];
  const float* Wk     = (const float*)d_in[2];
  const float* Wv     = (const float*)d_in[3];
  const float* Wg     = (const float*)d_in[4];
  const float* Wo     = (const float*)d_in[5];
  const float* lepe_w = (const float*)d_in[6];
  const float* lepe_b = (const float*)d_in[7];
  float* out = (float*)d_out;

  char* ws = (char*)d_ws;
  bf16*   Xb    = (bf16*)(ws);
  float*  kvp   = (float*)(ws);                  // aliases Xb (dead after proj)
  bf16*   Wcat  = (bf16*)(ws + 33554432);
  bf16*   Wob   = (bf16*)(ws + 41943040);
  float2* tab   = (float2*)(ws + 44040192);
  float*  ksump = (float*)(ws + 44040192);       // aliases tab (dead after proj)
  float*  vsump = (float*)(ws + 44302336);
  bf16*   QKVG  = (bf16*)(ws + 46137344);
  float*  ksum  = (float*)(ws + 180355072);
  float*  vsum  = (float*)(ws + 180371456);
  bf16*   kvT   = (bf16*)(ws + 180387840);
  bf16*   obuf  = (bf16*)(ws + 181960704);

  prep_kernel<<<22528, 256, 0, stream>>>(X, Wq, Wk, Wv, Wg, Wo, Xb, Wcat, Wob, tab);

  gemm_qkvg<<<1024, 512, 0, stream>>>(Xb, Wcat, QKVG, tab);

  kv_mfma<<<dim3(16, 32), 256, 0, stream>>>(QKVG, kvp, ksump, vsump);
  kv_reduce<<<2048, 256, 0, stream>>>(kvp, ksump, vsump, kvT, ksum, vsum);

  gemm_num<<<dim3(32, 8, 4), 256, 0, stream>>>(QKVG, kvT, ksum, vsum, lepe_w, lepe_b, obuf);

  gemm_final<<<1024, 256, 0, stream>>>(obuf, Wob, out);
}

// Round 9
// 390.774 us; speedup vs baseline: 2.4697x; 1.0058x over previous
//
#include <hip/hip_runtime.h>
#include <math.h>
#include <stdint.h>

// ---------------------------------------------------------------------------
// MalaAttention on MI355X (gfx950). Round 14:
//  - gemm_final: 256x256 8-phase port, SECOND attempt — round 6's regression
//    was the rule-#20 scratch spill (epilogue "#pragma unroll 1" made
//    acc[rbase+rf] runtime-indexed), not the structure. Now fully unrolled.
//    Grid 256 (64m x 4n), XCD m-partition, coalesced fp32 store via
//    float T2[64][260].
//  - everything else byte-identical to round 13 (393.0us best).
//
// Workspace layout (bytes):
//   Xb    @ 0          32MB  bf16 X        (dead after proj -> kvp)
//   kvp   @ 0          32MB  f32 [16][bh][128][128] kv partials
//   Wcat  @ 33554432    8MB  bf16 [Wq;Wk;Wv;Wg]
//   Wob   @ 41943040    2MB  bf16 Wo
//   tab   @ 44040192    2MB  float2 [4096][64] rope sin/cos (dead after proj)
//   ksump @ 44040192  256KB  f32 [16][bh][128]   (aliases tab)
//   vsump @ 44302336  256KB  f32 [16][bh][128]
//   QKVG  @ 46137344  128MB  bf16 [16384][4096] col blocks: q|k|v|g
//   ksum  @ 180355072  16KB  f32 [bh][128]
//   vsum  @ 180371456  16KB  f32 [bh][128]
//   kvT   @ 180387840   1MB  bf16 kvT[bh][e][d]
//   obuf  @ 181960704  32MB  bf16 gated out
// ---------------------------------------------------------------------------

typedef __bf16 bf16;
typedef __bf16 bf16x2 __attribute__((ext_vector_type(2)));
typedef __bf16 bf16x4 __attribute__((ext_vector_type(4)));
typedef __bf16 bf16x8 __attribute__((ext_vector_type(8)));
typedef float f32x4 __attribute__((ext_vector_type(4)));

static constexpr float kScale = 0.08838834764831845f; // 1/sqrt(128)

__device__ __forceinline__ void async_copy16(const void* g, void* l) {
  __builtin_amdgcn_global_load_lds(
      (const __attribute__((address_space(1))) void*)(uintptr_t)g,
      (__attribute__((address_space(3))) void*)(uintptr_t)l, 16, 0, 0);
}

// ---------------------------------------------------------------------------
// Proj GEMM: QKVG = Xb @ Wcat^T. 256x256 tile, BK=64, 8-phase schedule.
// Grid 1024 (64 m-tiles x 16 n-tiles), XCD m-partitioned. RoPE fused (by<8).
// ---------------------------------------------------------------------------
__global__ __launch_bounds__(512, 1) void gemm_qkvg(
    const bf16* __restrict__ A, const bf16* __restrict__ Bw,
    bf16* __restrict__ C, const float2* __restrict__ tab)
{
  __shared__ __align__(16) char smem[131072];

  const int t = threadIdx.x;
  const int bid = blockIdx.x;
  const int n = bid >> 3;
  const int bx = (bid & 7) * 8 + (n & 7);         // 8 m-tiles per XCD
  const int by = n >> 3;                          // 0..15
  const long m0 = (long)bx * 256;
  const long n0 = (long)by * 256;

  const int d0 = t * 16;
  const int dd = d0 ^ (((d0 >> 7) & 7) << 4);
  const int rT = dd >> 7;
  const int cT = (dd & 127) >> 1;
  const bf16* aSt = A  + (m0 + rT) * 1024 + cT;
  const bf16* bSt = Bw + (n0 + rT) * 1024 + cT;
  char* ldsDst = smem + d0;

  const int lane = t & 63, wid = t >> 6;
  const int wm = wid >> 2, wn = wid & 3;
  const int fm = lane & 15, fq = lane >> 4;
  const int xsw = (fm & 7) << 4;
  const int o0 = (fq * 16) ^ xsw;
  const int o1 = o0 ^ 64;
  const char* ldsA0 = smem + wm * 16384 + fm * 128 + o0;
  const char* ldsA1 = smem + wm * 16384 + fm * 128 + o1;
  const char* ldsB0 = smem + 32768 + (wn >> 1) * 16384 +
                      ((wn & 1) * 64 + fm) * 128 + o0;
  const char* ldsB1 = ldsB0 + (o1 - o0);

  f32x4 acc[8][4] = {};
  bf16x8 a4[4][2], b4[4][2];

#define STAGE_A(kt, h) do {                                                  \
    const bf16* s_ = aSt + (long)(h) * 131072 + (kt) * 64;                   \
    char* d_ = ldsDst + ((kt) & 1) * 65536 + (h) * 16384;                    \
    async_copy16(s_, d_);                                                    \
    async_copy16(s_ + 65536, d_ + 8192);                                     \
  } while (0)
#define STAGE_B(kt, h) do {                                                  \
    const bf16* s_ = bSt + (long)(h) * 131072 + (kt) * 64;                   \
    char* d_ = ldsDst + ((kt) & 1) * 65536 + 32768 + (h) * 16384;            \
    async_copy16(s_, d_);                                                    \
    async_copy16(s_ + 65536, d_ + 8192);                                     \
  } while (0)
#define LOAD_A(buf, qi) do {                                                 \
    const char* p0_ = ldsA0 + (buf) * 65536 + (qi) * 8192;                   \
    const char* p1_ = ldsA1 + (buf) * 65536 + (qi) * 8192;                   \
    a4[0][0] = *(const bf16x8*)(p0_);                                        \
    a4[0][1] = *(const bf16x8*)(p1_);                                        \
    a4[1][0] = *(const bf16x8*)(p0_ + 2048);                                 \
    a4[1][1] = *(const bf16x8*)(p1_ + 2048);                                 \
    a4[2][0] = *(const bf16x8*)(p0_ + 4096);                                 \
    a4[2][1] = *(const bf16x8*)(p1_ + 4096);                                 \
    a4[3][0] = *(const bf16x8*)(p0_ + 6144);                                 \
    a4[3][1] = *(const bf16x8*)(p1_ + 6144);                                 \
  } while (0)
#define LOAD_B(buf, qj) do {                                                 \
    const char* p0_ = ldsB0 + (buf) * 65536 + (qj) * 4096;                   \
    const char* p1_ = ldsB1 + (buf) * 65536 + (qj) * 4096;                   \
    b4[2*(qj)+0][0] = *(const bf16x8*)(p0_);                                 \
    b4[2*(qj)+0][1] = *(const bf16x8*)(p1_);                                 \
    b4[2*(qj)+1][0] = *(const bf16x8*)(p0_ + 2048);                          \
    b4[2*(qj)+1][1] = *(const bf16x8*)(p1_ + 2048);                          \
  } while (0)
#define MM1(i, j, ks)                                                        \
    acc[i][j] = __builtin_amdgcn_mfma_f32_16x16x32_bf16(                     \
        a4[(i) & 3][ks], b4[j][ks], acc[i][j], 0, 0, 0)
#define MFMA_Q(qi, qj) do {                                                  \
    MM1(4*(qi)+0, 2*(qj)+0, 0); MM1(4*(qi)+1, 2*(qj)+0, 0);                  \
    MM1(4*(qi)+2, 2*(qj)+0, 0); MM1(4*(qi)+3, 2*(qj)+0, 0);                  \
    MM1(4*(qi)+0, 2*(qj)+1, 0); MM1(4*(qi)+1, 2*(qj)+1, 0);                  \
    MM1(4*(qi)+2, 2*(qj)+1, 0); MM1(4*(qi)+3, 2*(qj)+1, 0);                  \
    MM1(4*(qi)+0, 2*(qj)+0, 1); MM1(4*(qi)+1, 2*(qj)+0, 1);                  \
    MM1(4*(qi)+2, 2*(qj)+0, 1); MM1(4*(qi)+3, 2*(qj)+0, 1);                  \
    MM1(4*(qi)+0, 2*(qj)+1, 1); MM1(4*(qi)+1, 2*(qj)+1, 1);                  \
    MM1(4*(qi)+2, 2*(qj)+1, 1); MM1(4*(qi)+3, 2*(qj)+1, 1);                  \
  } while (0)
#define BAR()    __builtin_amdgcn_s_barrier()
#define SCHEDB() __builtin_amdgcn_sched_barrier(0)
#define PRIO(p)  __builtin_amdgcn_s_setprio(p)

  STAGE_A(0, 0); STAGE_A(0, 1); STAGE_B(0, 0); STAGE_B(0, 1);
  STAGE_A(1, 0);
  asm volatile("s_waitcnt vmcnt(2)" ::: "memory");
  BAR(); SCHEDB();

#pragma unroll 1
  for (int it = 0; it < 7; ++it) {
    const int k1 = 2 * it + 1;
    const int k2 = 2 * it + 2;
    const int k3 = 2 * it + 3;
    LOAD_A(0, 0); LOAD_B(0, 0);
    STAGE_A(k1, 1);
    BAR(); SCHEDB(); PRIO(1); MFMA_Q(0, 0); PRIO(0); BAR(); SCHEDB();
    LOAD_B(0, 1);
    STAGE_B(k1, 0);
    BAR(); SCHEDB(); PRIO(1); MFMA_Q(0, 1); PRIO(0); BAR(); SCHEDB();
    LOAD_A(0, 1);
    STAGE_B(k1, 1);
    BAR(); SCHEDB(); PRIO(1); MFMA_Q(1, 1); PRIO(0); BAR(); SCHEDB();
    STAGE_A(k2, 0);
    BAR(); SCHEDB(); PRIO(1); MFMA_Q(1, 0); PRIO(0);
    asm volatile("s_waitcnt vmcnt(2)" ::: "memory");
    BAR(); SCHEDB();
    LOAD_A(1, 0); LOAD_B(1, 0);
    STAGE_A(k2, 1);
    BAR(); SCHEDB(); PRIO(1); MFMA_Q(0, 0); PRIO(0); BAR(); SCHEDB();
    LOAD_B(1, 1);
    STAGE_B(k2, 0);
    BAR(); SCHEDB(); PRIO(1); MFMA_Q(0, 1); PRIO(0); BAR(); SCHEDB();
    LOAD_A(1, 1);
    STAGE_B(k2, 1);
    BAR(); SCHEDB(); PRIO(1); MFMA_Q(1, 1); PRIO(0); BAR(); SCHEDB();
    STAGE_A(k3, 0);
    BAR(); SCHEDB(); PRIO(1); MFMA_Q(1, 0); PRIO(0);
    asm volatile("s_waitcnt vmcnt(2)" ::: "memory");
    BAR(); SCHEDB();
  }

  {
    LOAD_A(0, 0); LOAD_B(0, 0);
    STAGE_A(15, 1);
    BAR(); SCHEDB(); PRIO(1); MFMA_Q(0, 0); PRIO(0); BAR(); SCHEDB();
    LOAD_B(0, 1);
    STAGE_B(15, 0);
    BAR(); SCHEDB(); PRIO(1); MFMA_Q(0, 1); PRIO(0); BAR(); SCHEDB();
    LOAD_A(0, 1);
    STAGE_B(15, 1);
    BAR(); SCHEDB(); PRIO(1); MFMA_Q(1, 1); PRIO(0); BAR(); SCHEDB();
    BAR(); SCHEDB(); PRIO(1); MFMA_Q(1, 0); PRIO(0);
    asm volatile("s_waitcnt vmcnt(0)" ::: "memory");
    BAR(); SCHEDB();
    LOAD_A(1, 0); LOAD_B(1, 0);
    BAR(); SCHEDB(); PRIO(1); MFMA_Q(0, 0); PRIO(0); BAR(); SCHEDB();
    LOAD_B(1, 1);
    BAR(); SCHEDB(); PRIO(1); MFMA_Q(0, 1); PRIO(0); BAR(); SCHEDB();
    LOAD_A(1, 1);
    BAR(); SCHEDB(); PRIO(1); MFMA_Q(1, 1); PRIO(0); BAR(); SCHEDB();
    BAR(); SCHEDB(); PRIO(1); MFMA_Q(1, 0); PRIO(0); BAR(); SCHEDB();
  }

#undef LOAD_A
#undef LOAD_B

  // ---- epilogue: two 128-row half-passes through T[128][264] (RoPE by<8)
  bf16* T = (bf16*)smem;
  __syncthreads();
#pragma unroll 1
  for (int hw = 0; hw < 2; ++hw) {
    if (wm == hw) {
#pragma unroll
      for (int rf = 0; rf < 8; ++rf)
#pragma unroll
        for (int cf = 0; cf < 4; ++cf)
#pragma unroll
          for (int r = 0; r < 4; ++r)
            T[(rf * 16 + fq * 4 + r) * 264 + wn * 64 + cf * 16 + fm] =
                (bf16)acc[rf][cf][r];
    }
    __syncthreads();
    if (by < 8) {  // q|k region: RoPE pair rotation in LDS
#pragma unroll
      for (int ii = 0; ii < 32; ++ii) {
        const int pi = t + ii * 512;            // 16384 pairs
        const int row = pi >> 7, pr = pi & 127;
        const int hd = pr >> 6, i = pr & 63;
        const int c0 = hd * 128 + i;
        const int s = (int)((m0 + hw * 128 + row) & 4095);
        const float2 sc = tab[s * 64 + i];
        float x1 = (float)T[row * 264 + c0];
        float x2 = (float)T[row * 264 + c0 + 64];
        T[row * 264 + c0]      = (bf16)(x1 * sc.y - x2 * sc.x);
        T[row * 264 + c0 + 64] = (bf16)(x2 * sc.y + x1 * sc.x);
      }
      __syncthreads();
    }
#pragma unroll
    for (int ii = 0; ii < 8; ++ii) {
      const int cid = t + ii * 512;
      const int row = cid >> 5, ch = cid & 31;
      *(bf16x8*)(C + (m0 + hw * 128 + row) * 4096 + n0 + ch * 8) =
          *(const bf16x8*)(T + row * 264 + ch * 8);
    }
    __syncthreads();
  }
#undef STAGE_A
#undef STAGE_B
#undef MM1
#undef MFMA_Q
#undef BAR
#undef SCHEDB
#undef PRIO
}

// ---------------------------------------------------------------------------
// Final NT GEMM: out = obuf @ Wo^T, fp32 out. 256x256 tile, 8-phase.
// Grid 256 (64 m-tiles x 4 n-tiles), XCD m-partitioned, 1 block/CU.
// Epilogue: 4 quarter-passes through float T2[64][260], FULLY UNROLLED
// (rule #20: every acc index compile-time).
// ---------------------------------------------------------------------------
__global__ __launch_bounds__(512, 1) void gemm_final(
    const bf16* __restrict__ A, const bf16* __restrict__ Bw,
    float* __restrict__ C)
{
  __shared__ __align__(16) char smem[131072];

  const int t = threadIdx.x;
  const int bid = blockIdx.x;
  const int n = bid >> 3;
  const int bx = (bid & 7) * 8 + (n & 7);         // 64 m-tiles
  const int by = n >> 3;                          // 0..3
  const long m0 = (long)bx * 256;
  const long n0 = (long)by * 256;

  const int d0 = t * 16;
  const int dd = d0 ^ (((d0 >> 7) & 7) << 4);
  const int rT = dd >> 7;
  const int cT = (dd & 127) >> 1;
  const bf16* aSt = A  + (m0 + rT) * 1024 + cT;
  const bf16* bSt = Bw + (n0 + rT) * 1024 + cT;
  char* ldsDst = smem + d0;

  const int lane = t & 63, wid = t >> 6;
  const int wm = wid >> 2, wn = wid & 3;
  const int fm = lane & 15, fq = lane >> 4;
  const int xsw = (fm & 7) << 4;
  const int o0 = (fq * 16) ^ xsw;
  const int o1 = o0 ^ 64;
  const char* ldsA0 = smem + wm * 16384 + fm * 128 + o0;
  const char* ldsA1 = smem + wm * 16384 + fm * 128 + o1;
  const char* ldsB0 = smem + 32768 + (wn >> 1) * 16384 +
                      ((wn & 1) * 64 + fm) * 128 + o0;
  const char* ldsB1 = ldsB0 + (o1 - o0);

  f32x4 acc[8][4] = {};
  bf16x8 a4[4][2], b4[4][2];

#define STAGE_A(kt, h) do {                                                  \
    const bf16* s_ = aSt + (long)(h) * 131072 + (kt) * 64;                   \
    char* d_ = ldsDst + ((kt) & 1) * 65536 + (h) * 16384;                    \
    async_copy16(s_, d_);                                                    \
    async_copy16(s_ + 65536, d_ + 8192);                                     \
  } while (0)
#define STAGE_B(kt, h) do {                                                  \
    const bf16* s_ = bSt + (long)(h) * 131072 + (kt) * 64;                   \
    char* d_ = ldsDst + ((kt) & 1) * 65536 + 32768 + (h) * 16384;            \
    async_copy16(s_, d_);                                                    \
    async_copy16(s_ + 65536, d_ + 8192);                                     \
  } while (0)
#define LOAD_A(buf, qi) do {                                                 \
    const char* p0_ = ldsA0 + (buf) * 65536 + (qi) * 8192;                   \
    const char* p1_ = ldsA1 + (buf) * 65536 + (qi) * 8192;                   \
    a4[0][0] = *(const bf16x8*)(p0_);                                        \
    a4[0][1] = *(const bf16x8*)(p1_);                                        \
    a4[1][0] = *(const bf16x8*)(p0_ + 2048);                                 \
    a4[1][1] = *(const bf16x8*)(p1_ + 2048);                                 \
    a4[2][0] = *(const bf16x8*)(p0_ + 4096);                                 \
    a4[2][1] = *(const bf16x8*)(p1_ + 4096);                                 \
    a4[3][0] = *(const bf16x8*)(p0_ + 6144);                                 \
    a4[3][1] = *(const bf16x8*)(p1_ + 6144);                                 \
  } while (0)
#define LOAD_B(buf, qj) do {                                                 \
    const char* p0_ = ldsB0 + (buf) * 65536 + (qj) * 4096;                   \
    const char* p1_ = ldsB1 + (buf) * 65536 + (qj) * 4096;                   \
    b4[2*(qj)+0][0] = *(const bf16x8*)(p0_);                                 \
    b4[2*(qj)+0][1] = *(const bf16x8*)(p1_);                                 \
    b4[2*(qj)+1][0] = *(const bf16x8*)(p0_ + 2048);                          \
    b4[2*(qj)+1][1] = *(const bf16x8*)(p1_ + 2048);                          \
  } while (0)
#define MM1(i, j, ks)                                                        \
    acc[i][j] = __builtin_amdgcn_mfma_f32_16x16x32_bf16(                     \
        a4[(i) & 3][ks], b4[j][ks], acc[i][j], 0, 0, 0)
#define MFMA_Q(qi, qj) do {                                                  \
    MM1(4*(qi)+0, 2*(qj)+0, 0); MM1(4*(qi)+1, 2*(qj)+0, 0);                  \
    MM1(4*(qi)+2, 2*(qj)+0, 0); MM1(4*(qi)+3, 2*(qj)+0, 0);                  \
    MM1(4*(qi)+0, 2*(qj)+1, 0); MM1(4*(qi)+1, 2*(qj)+1, 0);                  \
    MM1(4*(qi)+2, 2*(qj)+1, 0); MM1(4*(qi)+3, 2*(qj)+1, 0);                  \
    MM1(4*(qi)+0, 2*(qj)+0, 1); MM1(4*(qi)+1, 2*(qj)+0, 1);                  \
    MM1(4*(qi)+2, 2*(qj)+0, 1); MM1(4*(qi)+3, 2*(qj)+0, 1);                  \
    MM1(4*(qi)+0, 2*(qj)+1, 1); MM1(4*(qi)+1, 2*(qj)+1, 1);                  \
    MM1(4*(qi)+2, 2*(qj)+1, 1); MM1(4*(qi)+3, 2*(qj)+1, 1);                  \
  } while (0)
#define BAR()    __builtin_amdgcn_s_barrier()
#define SCHEDB() __builtin_amdgcn_sched_barrier(0)
#define PRIO(p)  __builtin_amdgcn_s_setprio(p)

  STAGE_A(0, 0); STAGE_A(0, 1); STAGE_B(0, 0); STAGE_B(0, 1);
  STAGE_A(1, 0);
  asm volatile("s_waitcnt vmcnt(2)" ::: "memory");
  BAR(); SCHEDB();

#pragma unroll 1
  for (int it = 0; it < 7; ++it) {
    const int k1 = 2 * it + 1;
    const int k2 = 2 * it + 2;
    const int k3 = 2 * it + 3;
    LOAD_A(0, 0); LOAD_B(0, 0);
    STAGE_A(k1, 1);
    BAR(); SCHEDB(); PRIO(1); MFMA_Q(0, 0); PRIO(0); BAR(); SCHEDB();
    LOAD_B(0, 1);
    STAGE_B(k1, 0);
    BAR(); SCHEDB(); PRIO(1); MFMA_Q(0, 1); PRIO(0); BAR(); SCHEDB();
    LOAD_A(0, 1);
    STAGE_B(k1, 1);
    BAR(); SCHEDB(); PRIO(1); MFMA_Q(1, 1); PRIO(0); BAR(); SCHEDB();
    STAGE_A(k2, 0);
    BAR(); SCHEDB(); PRIO(1); MFMA_Q(1, 0); PRIO(0);
    asm volatile("s_waitcnt vmcnt(2)" ::: "memory");
    BAR(); SCHEDB();
    LOAD_A(1, 0); LOAD_B(1, 0);
    STAGE_A(k2, 1);
    BAR(); SCHEDB(); PRIO(1); MFMA_Q(0, 0); PRIO(0); BAR(); SCHEDB();
    LOAD_B(1, 1);
    STAGE_B(k2, 0);
    BAR(); SCHEDB(); PRIO(1); MFMA_Q(0, 1); PRIO(0); BAR(); SCHEDB();
    LOAD_A(1, 1);
    STAGE_B(k2, 1);
    BAR(); SCHEDB(); PRIO(1); MFMA_Q(1, 1); PRIO(0); BAR(); SCHEDB();
    STAGE_A(k3, 0);
    BAR(); SCHEDB(); PRIO(1); MFMA_Q(1, 0); PRIO(0);
    asm volatile("s_waitcnt vmcnt(2)" ::: "memory");
    BAR(); SCHEDB();
  }

  {
    LOAD_A(0, 0); LOAD_B(0, 0);
    STAGE_A(15, 1);
    BAR(); SCHEDB(); PRIO(1); MFMA_Q(0, 0); PRIO(0); BAR(); SCHEDB();
    LOAD_B(0, 1);
    STAGE_B(15, 0);
    BAR(); SCHEDB(); PRIO(1); MFMA_Q(0, 1); PRIO(0); BAR(); SCHEDB();
    LOAD_A(0, 1);
    STAGE_B(15, 1);
    BAR(); SCHEDB(); PRIO(1); MFMA_Q(1, 1); PRIO(0); BAR(); SCHEDB();
    BAR(); SCHEDB(); PRIO(1); MFMA_Q(1, 0); PRIO(0);
    asm volatile("s_waitcnt vmcnt(0)" ::: "memory");
    BAR(); SCHEDB();
    LOAD_A(1, 0); LOAD_B(1, 0);
    BAR(); SCHEDB(); PRIO(1); MFMA_Q(0, 0); PRIO(0); BAR(); SCHEDB();
    LOAD_B(1, 1);
    BAR(); SCHEDB(); PRIO(1); MFMA_Q(0, 1); PRIO(0); BAR(); SCHEDB();
    LOAD_A(1, 1);
    BAR(); SCHEDB(); PRIO(1); MFMA_Q(1, 1); PRIO(0); BAR(); SCHEDB();
    BAR(); SCHEDB(); PRIO(1); MFMA_Q(1, 0); PRIO(0); BAR(); SCHEDB();
  }

#undef STAGE_A
#undef STAGE_B
#undef LOAD_A
#undef LOAD_B
#undef MM1
#undef MFMA_Q
#undef BAR
#undef SCHEDB
#undef PRIO

  // ---- epilogue: 4 quarter-passes through float T2[64][260], FULL unroll
  float* T2 = (float*)smem;
  __syncthreads();
#pragma unroll
  for (int p = 0; p < 4; ++p) {
    if (wm == (p >> 1)) {
      const int rbase = (p & 1) * 4;            // compile-time (full unroll)
#pragma unroll
      for (int rf = 0; rf < 4; ++rf)
#pragma unroll
        for (int cf = 0; cf < 4; ++cf)
#pragma unroll
          for (int r = 0; r < 4; ++r)
            T2[(rf * 16 + fq * 4 + r) * 260 + wn * 64 + cf * 16 + fm] =
                acc[rbase + rf][cf][r];
    }
    __syncthreads();
#pragma unroll
    for (int ii = 0; ii < 8; ++ii) {
      const int cid = t + ii * 512;              // 4096 float4 chunks
      const int row = cid >> 6, ch = cid & 63;
      *(float4*)(C + (m0 + p * 64 + row) * 1024 + n0 + ch * 4) =
          *(const float4*)(T2 + row * 260 + ch * 4);
    }
    __syncthreads();
  }
}

// ---------------------------------------------------------------------------
// num GEMM (per b,h: M=4096 N=128 K=128) + fused den + mala/LePE/gate.
// Half-tile epilogue (T = 64x136); row-pair bf16x4 epilogue.
// ---------------------------------------------------------------------------
__global__ __launch_bounds__(256, 2) void gemm_num(
    const bf16* __restrict__ QKVG, const bf16* __restrict__ kvTall,
    const float* __restrict__ ksum, const float* __restrict__ vsum,
    const float* __restrict__ lepe_w, const float* __restrict__ lepe_b,
    bf16* __restrict__ obuf)
{
  __shared__ __align__(16) char smem[17408];
  bf16* As = (bf16*)smem;
  bf16* Bs = (bf16*)(smem + 8192);
  bf16* T  = (bf16*)smem;                      // epilogue, 64 rows, stride 136
  __shared__ float sden[128], svsum[128], slb[128], sksum[128];
  __shared__ float slw[5][128];

  const int t = threadIdx.x;
  const int h = blockIdx.y, b = blockIdx.z;
  const int bh = b * 8 + h;
  const long m0 = (long)blockIdx.x * 128;
  const bf16* A  = QKVG + (long)b * 16777216 + m0 * 4096 + h * 128;
  const bf16* Bw = kvTall + (long)bh * 16384;

  if (t < 128) {
    sksum[t] = ksum[bh * 128 + t];
    svsum[t] = vsum[bh * 128 + t];
    slb[t]   = lepe_b[h * 128 + t];
#pragma unroll
    for (int j = 0; j < 5; ++j) slw[j][t] = lepe_w[(h * 128 + t) * 5 + j];
  }

  const int i0 = t, i1 = t + 256;
  const bf16* gA0 = A + (long)(i0 >> 2) * 4096 + (i0 & 3) * 8;
  const bf16* gA1 = A + (long)(i1 >> 2) * 4096 + (i1 & 3) * 8;
  const bf16* gB0 = Bw + (long)(i0 >> 2) * 128 + (i0 & 3) * 8;
  const bf16* gB1 = Bw + (long)(i1 >> 2) * 128 + (i1 & 3) * 8;
  bf16* lA0 = As + i0 * 8; bf16* lA1 = As + i1 * 8;
  bf16* lB0 = Bs + i0 * 8; bf16* lB1 = Bs + i1 * 8;

  const int lane = t & 63, wv = t >> 6;
  const int moff = (wv & 1) * 64, noff = (wv >> 1) * 64;
  const int fm = lane & 15, fq = lane >> 4;

  f32x4 acc[4][4] = {};
  float dacc = 0.f;

  for (int k0 = 0; k0 < 128; k0 += 32) {
    async_copy16(gA0, lA0); async_copy16(gA1, lA1);
    async_copy16(gB0, lB0); async_copy16(gB1, lB1);
    gA0 += 32; gA1 += 32; gB0 += 32; gB1 += 32;
    __syncthreads();
    bf16x8 af[4], bfv[4];
#pragma unroll
    for (int i = 0; i < 4; ++i) {
      af[i]  = *(const bf16x8*)(As + (moff + i * 16 + fm) * 32 + fq * 8);
      bfv[i] = *(const bf16x8*)(Bs + (noff + i * 16 + fm) * 32 + fq * 8);
    }
#pragma unroll
    for (int i = 0; i < 4; ++i)
#pragma unroll
      for (int j = 0; j < 4; ++j)
        acc[i][j] = __builtin_amdgcn_mfma_f32_16x16x32_bf16(af[i], bfv[j], acc[i][j], 0, 0, 0);
    if (t < 128) {                 // den partial: row t, k-chunk k0..k0+32
#pragma unroll
      for (int c8 = 0; c8 < 4; ++c8) {
        bf16x8 q8 = *(const bf16x8*)(As + t * 32 + c8 * 8);
#pragma unroll
        for (int e = 0; e < 8; ++e) dacc += (float)q8[e] * sksum[k0 + c8 * 8 + e];
      }
    }
    __syncthreads();
  }
  if (t < 128) sden[t] = dacc * kScale + 4096.0f;

  // row-pair epilogue: lanes 0-31 -> even row cols 0..127 (4/lane),
  // lanes 32-63 -> odd row.
  const int lane32 = lane & 31, rsel = lane >> 5, c4 = lane32 * 4;
  float wj[5][4], lbv[4];
#pragma unroll
  for (int j = 0; j < 5; ++j)
#pragma unroll
    for (int cc = 0; cc < 4; ++cc) wj[j][cc] = slw[j][c4 + cc];
#pragma unroll
  for (int cc = 0; cc < 4; ++cc) lbv[cc] = slb[c4 + cc];

#pragma unroll
  for (int half = 0; half < 2; ++half) {
    if ((wv & 1) == half) {
#pragma unroll
      for (int i = 0; i < 4; ++i)
#pragma unroll
        for (int j = 0; j < 4; ++j)
#pragma unroll
          for (int r = 0; r < 4; ++r) {
            const int col = noff + j * 16 + fm;
            T[(i * 16 + fq * 4 + r) * 136 + col] = (bf16)(acc[i][j][r] * kScale + svsum[col]);
          }
    }
    __syncthreads();   // covers T (and sden on first pass)
    for (int rr = 0; rr < 8; ++rr) {
      const int lrow = wv * 16 + rr * 2 + rsel;  // 0..63
      const int row = half * 64 + lrow;          // 0..127 within tile
      const int s = (int)(m0 + row);
      const long grow = (long)b * 4096 + s;
      const float rden = 1.0f / sden[row];
      const bf16* vrow = QKVG + grow * 4096 + 2048 + h * 128 + c4;
      bf16x4 a4v = *(const bf16x4*)(T + lrow * 136 + c4);
      float lep[4] = {lbv[0], lbv[1], lbv[2], lbv[3]};
#pragma unroll
      for (int jt = 0; jt < 5; ++jt) {
        const int srow = s + jt - 2;
        if (srow >= 0 && srow < 4096) {
          bf16x4 v4 = *(const bf16x4*)(vrow + (long)(jt - 2) * 4096);
#pragma unroll
          for (int cc = 0; cc < 4; ++cc) lep[cc] += (float)v4[cc] * wj[jt][cc];
        }
      }
      bf16x4 g4 = *(const bf16x4*)(QKVG + grow * 4096 + 3072 + h * 128 + c4);
      bf16x4 o4;
#pragma unroll
      for (int cc = 0; cc < 4; ++cc)
        o4[cc] = (bf16)(((float)a4v[cc] * rden + lep[cc]) * (float)g4[cc]);
      *(bf16x4*)(obuf + grow * 1024 + h * 128 + c4) = o4;
    }
    __syncthreads();
  }
}

// ---------------------------------------------------------------------------
// prep: cast X->bf16, cast/concat weights, build rope sin/cos table.
// ---------------------------------------------------------------------------
__global__ void prep_kernel(const float* __restrict__ X, const float* __restrict__ Wq,
                            const float* __restrict__ Wk, const float* __restrict__ Wv,
                            const float* __restrict__ Wg, const float* __restrict__ Wo,
                            bf16* __restrict__ Xb, bf16* __restrict__ Wcat,
                            bf16* __restrict__ Wob, float2* __restrict__ tab)
{
  const int blk = blockIdx.x;
  if (blk < 16384) {
    long g = ((long)blk * 256 + threadIdx.x) * 4;
    float4 v = *(const float4*)(X + g);
    bf16x4 o = {(bf16)v.x, (bf16)v.y, (bf16)v.z, (bf16)v.w};
    *(bf16x4*)(Xb + g) = o;
  } else if (blk < 21504) {
    long g = ((long)(blk - 16384) * 256 + threadIdx.x) * 4;
    if (g < 4194304) {
      long idx = g & 1048575;
      int sel = (int)(g >> 20);
      const float* s = sel == 0 ? Wq : sel == 1 ? Wk : sel == 2 ? Wv : Wg;
      float4 v = *(const float4*)(s + idx);
      bf16x4 o = {(bf16)v.x, (bf16)v.y, (bf16)v.z, (bf16)v.w};
      *(bf16x4*)(Wcat + g) = o;
    } else {
      long idx = g - 4194304;
      float4 v = *(const float4*)(Wo + idx);
      bf16x4 o = {(bf16)v.x, (bf16)v.y, (bf16)v.z, (bf16)v.w};
      *(bf16x4*)(Wob + idx) = o;
    }
  } else {
    int idx = (blk - 21504) * 256 + threadIdx.x;
    int s = idx >> 6, i = idx & 63;
    float inv = powf(10000.0f, -((float)(2 * i)) / 128.0f);
    float ang = (float)s * inv;
    float sn, cs;
    sincosf(ang, &sn, &cs);
    tab[idx] = make_float2(sn, cs);
  }
}

// ---------------------------------------------------------------------------
// kv via MFMA with in-LDS transpose. Grid (16, 32) = 512 blocks (2/CU).
// kvp[chunk][bh][e][d] = sum_s v[s][e] k[s][d]; + ksum/vsum partials.
// ---------------------------------------------------------------------------
__global__ __launch_bounds__(256, 2) void kv_mfma(
    const bf16* __restrict__ QKVG, float* __restrict__ kvp,
    float* __restrict__ ksump, float* __restrict__ vsump)
{
  __shared__ __align__(16) bf16 VT[128 * 40];
  __shared__ __align__(16) bf16 KT[128 * 40];
  const int t = threadIdx.x;
  const int chunk = blockIdx.x, bh = blockIdx.y;
  const int b = bh >> 3, h = bh & 7;
  const long rowbase = ((long)b * 4096 + chunk * 256) * 4096 + h * 128;
  const bf16* Kg = QKVG + rowbase + 1024;
  const bf16* Vg = QKVG + rowbase + 2048;

  const int sp = t >> 4, fc = t & 15;
  const int lane = t & 63, wv = t >> 6;
  const int eoff = (wv & 1) * 64, doff = (wv >> 1) * 64;
  const int fm = lane & 15, fq = lane >> 4;
  const int srow = t & 127;
  const bool sumK = t >= 128;

  f32x4 acc[4][4] = {};
  float rsum = 0.f;

  for (int sb = 0; sb < 256; sb += 32) {
    const long go = (long)(sb + 2 * sp) * 4096 + fc * 8;
    bf16x8 v0 = *(const bf16x8*)(Vg + go);
    bf16x8 v1 = *(const bf16x8*)(Vg + go + 4096);
    bf16x8 k0 = *(const bf16x8*)(Kg + go);
    bf16x8 k1 = *(const bf16x8*)(Kg + go + 4096);
#pragma unroll
    for (int j = 0; j < 8; ++j) {
      const int f = fc * 8 + j;
      bf16x2 vp2 = {v0[j], v1[j]};
      bf16x2 kp2 = {k0[j], k1[j]};
      *(bf16x2*)(VT + f * 40 + 2 * sp) = vp2;
      *(bf16x2*)(KT + f * 40 + 2 * sp) = kp2;
    }
    __syncthreads();
    bf16x8 af[4], bfv[4];
#pragma unroll
    for (int i = 0; i < 4; ++i) {
      af[i]  = *(const bf16x8*)(VT + (eoff + i * 16 + fm) * 40 + fq * 8);
      bfv[i] = *(const bf16x8*)(KT + (doff + i * 16 + fm) * 40 + fq * 8);
    }
#pragma unroll
    for (int i = 0; i < 4; ++i)
#pragma unroll
      for (int j = 0; j < 4; ++j)
        acc[i][j] = __builtin_amdgcn_mfma_f32_16x16x32_bf16(af[i], bfv[j], acc[i][j], 0, 0, 0);
    const bf16* rp = (sumK ? KT : VT) + srow * 40;
#pragma unroll
    for (int i = 0; i < 4; ++i) {
      bf16x8 r8 = *(const bf16x8*)(rp + i * 8);
#pragma unroll
      for (int j = 0; j < 8; ++j) rsum += (float)r8[j];
    }
    __syncthreads();
  }

  float* plane = kvp + ((long)chunk * 32 + bh) * 16384;
#pragma unroll
  for (int i = 0; i < 4; ++i)
#pragma unroll
    for (int j = 0; j < 4; ++j)
#pragma unroll
      for (int r = 0; r < 4; ++r)
        plane[(long)(eoff + i * 16 + fq * 4 + r) * 128 + (doff + j * 16 + fm)] = acc[i][j][r];
  float* sdst = (sumK ? ksump : vsump) + ((long)chunk * 32 + bh) * 128 + srow;
  *sdst = rsum;
}

// Fold 16 chunk partials -> bf16 kvT + f32 ksum/vsum.
__global__ void kv_reduce(const float* __restrict__ kvp, const float* __restrict__ ksump,
                          const float* __restrict__ vsump, bf16* __restrict__ kvT,
                          float* __restrict__ ksum, float* __restrict__ vsum)
{
  long g = (long)blockIdx.x * 256 + threadIdx.x;
  long bh = g >> 14, idx = g & 16383;
  float s = 0.f;
#pragma unroll
  for (int c = 0; c < 16; ++c) s += kvp[((long)c * 32 + bh) * 16384 + idx];
  kvT[g] = (bf16)s;
  if (g < 8192) {
    int bh2 = (int)(g >> 8), rem = (int)(g & 255), f = rem & 127;
    const float* src = (rem >> 7) ? ksump : vsump;
    float* dst = (rem >> 7) ? ksum : vsum;
    float s2 = 0.f;
#pragma unroll
    for (int c = 0; c < 16; ++c) s2 += src[((long)c * 32 + bh2) * 128 + f];
    dst[bh2 * 128 + f] = s2;
  }
}

// ---------------------------------------------------------------------------
extern "C" void kernel_launch(void* const* d_in, const int* in_sizes, int n_in,
                              void* d_out, int out_size, void* d_ws, size_t ws_size,
                              hipStream_t stream)
{
  const float* X      = (const float*)d_in[0];
  const float* Wq     = (const float*)d_in[1];
  const float* Wk     = (const float*)d_in[2];
  const float* Wv     = (const float*)d_in[3];
  const float* Wg     = (const float*)d_in[4];
  const float* Wo     = (const float*)d_in[5];
  const float* lepe_w = (const float*)d_in[6];
  const float* lepe_b = (const float*)d_in[7];
  float* out = (float*)d_out;

  char* ws = (char*)d_ws;
  bf16*   Xb    = (bf16*)(ws);
  float*  kvp   = (float*)(ws);                  // aliases Xb (dead after proj)
  bf16*   Wcat  = (bf16*)(ws + 33554432);
  bf16*   Wob   = (bf16*)(ws + 41943040);
  float2* tab   = (float2*)(ws + 44040192);
  float*  ksump = (float*)(ws + 44040192);       // aliases tab (dead after proj)
  float*  vsump = (float*)(ws + 44302336);
  bf16*   QKVG  = (bf16*)(ws + 46137344);
  float*  ksum  = (float*)(ws + 180355072);
  float*  vsum  = (float*)(ws + 180371456);
  bf16*   kvT   = (bf16*)(ws + 180387840);
  bf16*   obuf  = (bf16*)(ws + 181960704);

  prep_kernel<<<22528, 256, 0, stream>>>(X, Wq, Wk, Wv, Wg, Wo, Xb, Wcat, Wob, tab);

  gemm_qkvg<<<1024, 512, 0, stream>>>(Xb, Wcat, QKVG, tab);

  kv_mfma<<<dim3(16, 32), 256, 0, stream>>>(QKVG, kvp, ksump, vsump);
  kv_reduce<<<2048, 256, 0, stream>>>(kvp, ksump, vsump, kvT, ksum, vsum);

  gemm_num<<<dim3(32, 8, 4), 256, 0, stream>>>(QKVG, kvT, ksum, vsum, lepe_w, lepe_b, obuf);

  gemm_final<<<256, 512, 0, stream>>>(obuf, Wob, out);
}

// Round 10
// 380.043 us; speedup vs baseline: 2.5394x; 1.0282x over previous
//
#include <hip/hip_runtime.h>
#include <math.h>
#include <stdint.h>

// ---------------------------------------------------------------------------
// MalaAttention on MI355X (gfx950). Round 15:
//  - kv_mfma: fix 16-way LDS write conflict in the in-LDS transpose.
//    Row stride 40 bf16 = 20 dw; f-step 8 = 160 dw === 0 mod 32, so all 16
//    fc-lanes wrote one bank. Fix: XOR-swizzle 16B s-units (unit ^= (f>>3)&3)
//    on BOTH write and fragment-read; rsum loop unaffected (sums all units).
//    Write conflicts 16-way -> 4-way.
//  - kv_reduce: float4/bf16x4 vectorized (512 blocks).
//  - everything else identical to round 14 (390.8us best).
//
// Workspace layout (bytes):
//   Xb    @ 0          32MB  bf16 X        (dead after proj -> kvp)
//   kvp   @ 0          32MB  f32 [16][bh][128][128] kv partials
//   Wcat  @ 33554432    8MB  bf16 [Wq;Wk;Wv;Wg]
//   Wob   @ 41943040    2MB  bf16 Wo
//   tab   @ 44040192    2MB  float2 [4096][64] rope sin/cos (dead after proj)
//   ksump @ 44040192  256KB  f32 [16][bh][128]   (aliases tab)
//   vsump @ 44302336  256KB  f32 [16][bh][128]
//   QKVG  @ 46137344  128MB  bf16 [16384][4096] col blocks: q|k|v|g
//   ksum  @ 180355072  16KB  f32 [bh][128]
//   vsum  @ 180371456  16KB  f32 [bh][128]
//   kvT   @ 180387840   1MB  bf16 kvT[bh][e][d]
//   obuf  @ 181960704  32MB  bf16 gated out
// ---------------------------------------------------------------------------

typedef __bf16 bf16;
typedef __bf16 bf16x2 __attribute__((ext_vector_type(2)));
typedef __bf16 bf16x4 __attribute__((ext_vector_type(4)));
typedef __bf16 bf16x8 __attribute__((ext_vector_type(8)));
typedef float f32x4 __attribute__((ext_vector_type(4)));

static constexpr float kScale = 0.08838834764831845f; // 1/sqrt(128)

__device__ __forceinline__ void async_copy16(const void* g, void* l) {
  __builtin_amdgcn_global_load_lds(
      (const __attribute__((address_space(1))) void*)(uintptr_t)g,
      (__attribute__((address_space(3))) void*)(uintptr_t)l, 16, 0, 0);
}

// ---------------------------------------------------------------------------
// Proj GEMM: QKVG = Xb @ Wcat^T. 256x256 tile, BK=64, 8-phase schedule.
// Grid 1024 (64 m-tiles x 16 n-tiles), XCD m-partitioned. RoPE fused (by<8).
// ---------------------------------------------------------------------------
__global__ __launch_bounds__(512, 1) void gemm_qkvg(
    const bf16* __restrict__ A, const bf16* __restrict__ Bw,
    bf16* __restrict__ C, const float2* __restrict__ tab)
{
  __shared__ __align__(16) char smem[131072];

  const int t = threadIdx.x;
  const int bid = blockIdx.x;
  const int n = bid >> 3;
  const int bx = (bid & 7) * 8 + (n & 7);         // 8 m-tiles per XCD
  const int by = n >> 3;                          // 0..15
  const long m0 = (long)bx * 256;
  const long n0 = (long)by * 256;

  const int d0 = t * 16;
  const int dd = d0 ^ (((d0 >> 7) & 7) << 4);
  const int rT = dd >> 7;
  const int cT = (dd & 127) >> 1;
  const bf16* aSt = A  + (m0 + rT) * 1024 + cT;
  const bf16* bSt = Bw + (n0 + rT) * 1024 + cT;
  char* ldsDst = smem + d0;

  const int lane = t & 63, wid = t >> 6;
  const int wm = wid >> 2, wn = wid & 3;
  const int fm = lane & 15, fq = lane >> 4;
  const int xsw = (fm & 7) << 4;
  const int o0 = (fq * 16) ^ xsw;
  const int o1 = o0 ^ 64;
  const char* ldsA0 = smem + wm * 16384 + fm * 128 + o0;
  const char* ldsA1 = smem + wm * 16384 + fm * 128 + o1;
  const char* ldsB0 = smem + 32768 + (wn >> 1) * 16384 +
                      ((wn & 1) * 64 + fm) * 128 + o0;
  const char* ldsB1 = ldsB0 + (o1 - o0);

  f32x4 acc[8][4] = {};
  bf16x8 a4[4][2], b4[4][2];

#define STAGE_A(kt, h) do {                                                  \
    const bf16* s_ = aSt + (long)(h) * 131072 + (kt) * 64;                   \
    char* d_ = ldsDst + ((kt) & 1) * 65536 + (h) * 16384;                    \
    async_copy16(s_, d_);                                                    \
    async_copy16(s_ + 65536, d_ + 8192);                                     \
  } while (0)
#define STAGE_B(kt, h) do {                                                  \
    const bf16* s_ = bSt + (long)(h) * 131072 + (kt) * 64;                   \
    char* d_ = ldsDst + ((kt) & 1) * 65536 + 32768 + (h) * 16384;            \
    async_copy16(s_, d_);                                                    \
    async_copy16(s_ + 65536, d_ + 8192);                                     \
  } while (0)
#define LOAD_A(buf, qi) do {                                                 \
    const char* p0_ = ldsA0 + (buf) * 65536 + (qi) * 8192;                   \
    const char* p1_ = ldsA1 + (buf) * 65536 + (qi) * 8192;                   \
    a4[0][0] = *(const bf16x8*)(p0_);                                        \
    a4[0][1] = *(const bf16x8*)(p1_);                                        \
    a4[1][0] = *(const bf16x8*)(p0_ + 2048);                                 \
    a4[1][1] = *(const bf16x8*)(p1_ + 2048);                                 \
    a4[2][0] = *(const bf16x8*)(p0_ + 4096);                                 \
    a4[2][1] = *(const bf16x8*)(p1_ + 4096);                                 \
    a4[3][0] = *(const bf16x8*)(p0_ + 6144);                                 \
    a4[3][1] = *(const bf16x8*)(p1_ + 6144);                                 \
  } while (0)
#define LOAD_B(buf, qj) do {                                                 \
    const char* p0_ = ldsB0 + (buf) * 65536 + (qj) * 4096;                   \
    const char* p1_ = ldsB1 + (buf) * 65536 + (qj) * 4096;                   \
    b4[2*(qj)+0][0] = *(const bf16x8*)(p0_);                                 \
    b4[2*(qj)+0][1] = *(const bf16x8*)(p1_);                                 \
    b4[2*(qj)+1][0] = *(const bf16x8*)(p0_ + 2048);                          \
    b4[2*(qj)+1][1] = *(const bf16x8*)(p1_ + 2048);                          \
  } while (0)
#define MM1(i, j, ks)                                                        \
    acc[i][j] = __builtin_amdgcn_mfma_f32_16x16x32_bf16(                     \
        a4[(i) & 3][ks], b4[j][ks], acc[i][j], 0, 0, 0)
#define MFMA_Q(qi, qj) do {                                                  \
    MM1(4*(qi)+0, 2*(qj)+0, 0); MM1(4*(qi)+1, 2*(qj)+0, 0);                  \
    MM1(4*(qi)+2, 2*(qj)+0, 0); MM1(4*(qi)+3, 2*(qj)+0, 0);                  \
    MM1(4*(qi)+0, 2*(qj)+1, 0); MM1(4*(qi)+1, 2*(qj)+1, 0);                  \
    MM1(4*(qi)+2, 2*(qj)+1, 0); MM1(4*(qi)+3, 2*(qj)+1, 0);                  \
    MM1(4*(qi)+0, 2*(qj)+0, 1); MM1(4*(qi)+1, 2*(qj)+0, 1);                  \
    MM1(4*(qi)+2, 2*(qj)+0, 1); MM1(4*(qi)+3, 2*(qj)+0, 1);                  \
    MM1(4*(qi)+0, 2*(qj)+1, 1); MM1(4*(qi)+1, 2*(qj)+1, 1);                  \
    MM1(4*(qi)+2, 2*(qj)+1, 1); MM1(4*(qi)+3, 2*(qj)+1, 1);                  \
  } while (0)
#define BAR()    __builtin_amdgcn_s_barrier()
#define SCHEDB() __builtin_amdgcn_sched_barrier(0)
#define PRIO(p)  __builtin_amdgcn_s_setprio(p)

  STAGE_A(0, 0); STAGE_A(0, 1); STAGE_B(0, 0); STAGE_B(0, 1);
  STAGE_A(1, 0);
  asm volatile("s_waitcnt vmcnt(2)" ::: "memory");
  BAR(); SCHEDB();

#pragma unroll 1
  for (int it = 0; it < 7; ++it) {
    const int k1 = 2 * it + 1;
    const int k2 = 2 * it + 2;
    const int k3 = 2 * it + 3;
    LOAD_A(0, 0); LOAD_B(0, 0);
    STAGE_A(k1, 1);
    BAR(); SCHEDB(); PRIO(1); MFMA_Q(0, 0); PRIO(0); BAR(); SCHEDB();
    LOAD_B(0, 1);
    STAGE_B(k1, 0);
    BAR(); SCHEDB(); PRIO(1); MFMA_Q(0, 1); PRIO(0); BAR(); SCHEDB();
    LOAD_A(0, 1);
    STAGE_B(k1, 1);
    BAR(); SCHEDB(); PRIO(1); MFMA_Q(1, 1); PRIO(0); BAR(); SCHEDB();
    STAGE_A(k2, 0);
    BAR(); SCHEDB(); PRIO(1); MFMA_Q(1, 0); PRIO(0);
    asm volatile("s_waitcnt vmcnt(2)" ::: "memory");
    BAR(); SCHEDB();
    LOAD_A(1, 0); LOAD_B(1, 0);
    STAGE_A(k2, 1);
    BAR(); SCHEDB(); PRIO(1); MFMA_Q(0, 0); PRIO(0); BAR(); SCHEDB();
    LOAD_B(1, 1);
    STAGE_B(k2, 0);
    BAR(); SCHEDB(); PRIO(1); MFMA_Q(0, 1); PRIO(0); BAR(); SCHEDB();
    LOAD_A(1, 1);
    STAGE_B(k2, 1);
    BAR(); SCHEDB(); PRIO(1); MFMA_Q(1, 1); PRIO(0); BAR(); SCHEDB();
    STAGE_A(k3, 0);
    BAR(); SCHEDB(); PRIO(1); MFMA_Q(1, 0); PRIO(0);
    asm volatile("s_waitcnt vmcnt(2)" ::: "memory");
    BAR(); SCHEDB();
  }

  {
    LOAD_A(0, 0); LOAD_B(0, 0);
    STAGE_A(15, 1);
    BAR(); SCHEDB(); PRIO(1); MFMA_Q(0, 0); PRIO(0); BAR(); SCHEDB();
    LOAD_B(0, 1);
    STAGE_B(15, 0);
    BAR(); SCHEDB(); PRIO(1); MFMA_Q(0, 1); PRIO(0); BAR(); SCHEDB();
    LOAD_A(0, 1);
    STAGE_B(15, 1);
    BAR(); SCHEDB(); PRIO(1); MFMA_Q(1, 1); PRIO(0); BAR(); SCHEDB();
    BAR(); SCHEDB(); PRIO(1); MFMA_Q(1, 0); PRIO(0);
    asm volatile("s_waitcnt vmcnt(0)" ::: "memory");
    BAR(); SCHEDB();
    LOAD_A(1, 0); LOAD_B(1, 0);
    BAR(); SCHEDB(); PRIO(1); MFMA_Q(0, 0); PRIO(0); BAR(); SCHEDB();
    LOAD_B(1, 1);
    BAR(); SCHEDB(); PRIO(1); MFMA_Q(0, 1); PRIO(0); BAR(); SCHEDB();
    LOAD_A(1, 1);
    BAR(); SCHEDB(); PRIO(1); MFMA_Q(1, 1); PRIO(0); BAR(); SCHEDB();
    BAR(); SCHEDB(); PRIO(1); MFMA_Q(1, 0); PRIO(0); BAR(); SCHEDB();
  }

#undef LOAD_A
#undef LOAD_B

  // ---- epilogue: two 128-row half-passes through T[128][264] (RoPE by<8)
  bf16* T = (bf16*)smem;
  __syncthreads();
#pragma unroll 1
  for (int hw = 0; hw < 2; ++hw) {
    if (wm == hw) {
#pragma unroll
      for (int rf = 0; rf < 8; ++rf)
#pragma unroll
        for (int cf = 0; cf < 4; ++cf)
#pragma unroll
          for (int r = 0; r < 4; ++r)
            T[(rf * 16 + fq * 4 + r) * 264 + wn * 64 + cf * 16 + fm] =
                (bf16)acc[rf][cf][r];
    }
    __syncthreads();
    if (by < 8) {  // q|k region: RoPE pair rotation in LDS
#pragma unroll
      for (int ii = 0; ii < 32; ++ii) {
        const int pi = t + ii * 512;            // 16384 pairs
        const int row = pi >> 7, pr = pi & 127;
        const int hd = pr >> 6, i = pr & 63;
        const int c0 = hd * 128 + i;
        const int s = (int)((m0 + hw * 128 + row) & 4095);
        const float2 sc = tab[s * 64 + i];
        float x1 = (float)T[row * 264 + c0];
        float x2 = (float)T[row * 264 + c0 + 64];
        T[row * 264 + c0]      = (bf16)(x1 * sc.y - x2 * sc.x);
        T[row * 264 + c0 + 64] = (bf16)(x2 * sc.y + x1 * sc.x);
      }
      __syncthreads();
    }
#pragma unroll
    for (int ii = 0; ii < 8; ++ii) {
      const int cid = t + ii * 512;
      const int row = cid >> 5, ch = cid & 31;
      *(bf16x8*)(C + (m0 + hw * 128 + row) * 4096 + n0 + ch * 8) =
          *(const bf16x8*)(T + row * 264 + ch * 8);
    }
    __syncthreads();
  }
#undef STAGE_A
#undef STAGE_B
#undef MM1
#undef MFMA_Q
#undef BAR
#undef SCHEDB
#undef PRIO
}

// ---------------------------------------------------------------------------
// Final NT GEMM: out = obuf @ Wo^T, fp32 out. 256x256 tile, 8-phase.
// Grid 256 (64 m-tiles x 4 n-tiles), XCD m-partitioned, 1 block/CU.
// Epilogue: 4 quarter-passes through float T2[64][260], FULLY UNROLLED.
// ---------------------------------------------------------------------------
__global__ __launch_bounds__(512, 1) void gemm_final(
    const bf16* __restrict__ A, const bf16* __restrict__ Bw,
    float* __restrict__ C)
{
  __shared__ __align__(16) char smem[131072];

  const int t = threadIdx.x;
  const int bid = blockIdx.x;
  const int n = bid >> 3;
  const int bx = (bid & 7) * 8 + (n & 7);         // 64 m-tiles
  const int by = n >> 3;                          // 0..3
  const long m0 = (long)bx * 256;
  const long n0 = (long)by * 256;

  const int d0 = t * 16;
  const int dd = d0 ^ (((d0 >> 7) & 7) << 4);
  const int rT = dd >> 7;
  const int cT = (dd & 127) >> 1;
  const bf16* aSt = A  + (m0 + rT) * 1024 + cT;
  const bf16* bSt = Bw + (n0 + rT) * 1024 + cT;
  char* ldsDst = smem + d0;

  const int lane = t & 63, wid = t >> 6;
  const int wm = wid >> 2, wn = wid & 3;
  const int fm = lane & 15, fq = lane >> 4;
  const int xsw = (fm & 7) << 4;
  const int o0 = (fq * 16) ^ xsw;
  const int o1 = o0 ^ 64;
  const char* ldsA0 = smem + wm * 16384 + fm * 128 + o0;
  const char* ldsA1 = smem + wm * 16384 + fm * 128 + o1;
  const char* ldsB0 = smem + 32768 + (wn >> 1) * 16384 +
                      ((wn & 1) * 64 + fm) * 128 + o0;
  const char* ldsB1 = ldsB0 + (o1 - o0);

  f32x4 acc[8][4] = {};
  bf16x8 a4[4][2], b4[4][2];

#define STAGE_A(kt, h) do {                                                  \
    const bf16* s_ = aSt + (long)(h) * 131072 + (kt) * 64;                   \
    char* d_ = ldsDst + ((kt) & 1) * 65536 + (h) * 16384;                    \
    async_copy16(s_, d_);                                                    \
    async_copy16(s_ + 65536, d_ + 8192);                                     \
  } while (0)
#define STAGE_B(kt, h) do {                                                  \
    const bf16* s_ = bSt + (long)(h) * 131072 + (kt) * 64;                   \
    char* d_ = ldsDst + ((kt) & 1) * 65536 + 32768 + (h) * 16384;            \
    async_copy16(s_, d_);                                                    \
    async_copy16(s_ + 65536, d_ + 8192);                                     \
  } while (0)
#define LOAD_A(buf, qi) do {                                                 \
    const char* p0_ = ldsA0 + (buf) * 65536 + (qi) * 8192;                   \
    const char* p1_ = ldsA1 + (buf) * 65536 + (qi) * 8192;                   \
    a4[0][0] = *(const bf16x8*)(p0_);                                        \
    a4[0][1] = *(const bf16x8*)(p1_);                                        \
    a4[1][0] = *(const bf16x8*)(p0_ + 2048);                                 \
    a4[1][1] = *(const bf16x8*)(p1_ + 2048);                                 \
    a4[2][0] = *(const bf16x8*)(p0_ + 4096);                                 \
    a4[2][1] = *(const bf16x8*)(p1_ + 4096);                                 \
    a4[3][0] = *(const bf16x8*)(p0_ + 6144);                                 \
    a4[3][1] = *(const bf16x8*)(p1_ + 6144);                                 \
  } while (0)
#define LOAD_B(buf, qj) do {                                                 \
    const char* p0_ = ldsB0 + (buf) * 65536 + (qj) * 4096;                   \
    const char* p1_ = ldsB1 + (buf) * 65536 + (qj) * 4096;                   \
    b4[2*(qj)+0][0] = *(const bf16x8*)(p0_);                                 \
    b4[2*(qj)+0][1] = *(const bf16x8*)(p1_);                                 \
    b4[2*(qj)+1][0] = *(const bf16x8*)(p0_ + 2048);                          \
    b4[2*(qj)+1][1] = *(const bf16x8*)(p1_ + 2048);                          \
  } while (0)
#define MM1(i, j, ks)                                                        \
    acc[i][j] = __builtin_amdgcn_mfma_f32_16x16x32_bf16(                     \
        a4[(i) & 3][ks], b4[j][ks], acc[i][j], 0, 0, 0)
#define MFMA_Q(qi, qj) do {                                                  \
    MM1(4*(qi)+0, 2*(qj)+0, 0); MM1(4*(qi)+1, 2*(qj)+0, 0);                  \
    MM1(4*(qi)+2, 2*(qj)+0, 0); MM1(4*(qi)+3, 2*(qj)+0, 0);                  \
    MM1(4*(qi)+0, 2*(qj)+1, 0); MM1(4*(qi)+1, 2*(qj)+1, 0);                  \
    MM1(4*(qi)+2, 2*(qj)+1, 0); MM1(4*(qi)+3, 2*(qj)+1, 0);                  \
    MM1(4*(qi)+0, 2*(qj)+0, 1); MM1(4*(qi)+1, 2*(qj)+0, 1);                  \
    MM1(4*(qi)+2, 2*(qj)+0, 1); MM1(4*(qi)+3, 2*(qj)+0, 1);                  \
    MM1(4*(qi)+0, 2*(qj)+1, 1); MM1(4*(qi)+1, 2*(qj)+1, 1);                  \
    MM1(4*(qi)+2, 2*(qj)+1, 1); MM1(4*(qi)+3, 2*(qj)+1, 1);                  \
  } while (0)
#define BAR()    __builtin_amdgcn_s_barrier()
#define SCHEDB() __builtin_amdgcn_sched_barrier(0)
#define PRIO(p)  __builtin_amdgcn_s_setprio(p)

  STAGE_A(0, 0); STAGE_A(0, 1); STAGE_B(0, 0); STAGE_B(0, 1);
  STAGE_A(1, 0);
  asm volatile("s_waitcnt vmcnt(2)" ::: "memory");
  BAR(); SCHEDB();

#pragma unroll 1
  for (int it = 0; it < 7; ++it) {
    const int k1 = 2 * it + 1;
    const int k2 = 2 * it + 2;
    const int k3 = 2 * it + 3;
    LOAD_A(0, 0); LOAD_B(0, 0);
    STAGE_A(k1, 1);
    BAR(); SCHEDB(); PRIO(1); MFMA_Q(0, 0); PRIO(0); BAR(); SCHEDB();
    LOAD_B(0, 1);
    STAGE_B(k1, 0);
    BAR(); SCHEDB(); PRIO(1); MFMA_Q(0, 1); PRIO(0); BAR(); SCHEDB();
    LOAD_A(0, 1);
    STAGE_B(k1, 1);
    BAR(); SCHEDB(); PRIO(1); MFMA_Q(1, 1); PRIO(0); BAR(); SCHEDB();
    STAGE_A(k2, 0);
    BAR(); SCHEDB(); PRIO(1); MFMA_Q(1, 0); PRIO(0);
    asm volatile("s_waitcnt vmcnt(2)" ::: "memory");
    BAR(); SCHEDB();
    LOAD_A(1, 0); LOAD_B(1, 0);
    STAGE_A(k2, 1);
    BAR(); SCHEDB(); PRIO(1); MFMA_Q(0, 0); PRIO(0); BAR(); SCHEDB();
    LOAD_B(1, 1);
    STAGE_B(k2, 0);
    BAR(); SCHEDB(); PRIO(1); MFMA_Q(0, 1); PRIO(0); BAR(); SCHEDB();
    LOAD_A(1, 1);
    STAGE_B(k2, 1);
    BAR(); SCHEDB(); PRIO(1); MFMA_Q(1, 1); PRIO(0); BAR(); SCHEDB();
    STAGE_A(k3, 0);
    BAR(); SCHEDB(); PRIO(1); MFMA_Q(1, 0); PRIO(0);
    asm volatile("s_waitcnt vmcnt(2)" ::: "memory");
    BAR(); SCHEDB();
  }

  {
    LOAD_A(0, 0); LOAD_B(0, 0);
    STAGE_A(15, 1);
    BAR(); SCHEDB(); PRIO(1); MFMA_Q(0, 0); PRIO(0); BAR(); SCHEDB();
    LOAD_B(0, 1);
    STAGE_B(15, 0);
    BAR(); SCHEDB(); PRIO(1); MFMA_Q(0, 1); PRIO(0); BAR(); SCHEDB();
    LOAD_A(0, 1);
    STAGE_B(15, 1);
    BAR(); SCHEDB(); PRIO(1); MFMA_Q(1, 1); PRIO(0); BAR(); SCHEDB();
    BAR(); SCHEDB(); PRIO(1); MFMA_Q(1, 0); PRIO(0);
    asm volatile("s_waitcnt vmcnt(0)" ::: "memory");
    BAR(); SCHEDB();
    LOAD_A(1, 0); LOAD_B(1, 0);
    BAR(); SCHEDB(); PRIO(1); MFMA_Q(0, 0); PRIO(0); BAR(); SCHEDB();
    LOAD_B(1, 1);
    BAR(); SCHEDB(); PRIO(1); MFMA_Q(0, 1); PRIO(0); BAR(); SCHEDB();
    LOAD_A(1, 1);
    BAR(); SCHEDB(); PRIO(1); MFMA_Q(1, 1); PRIO(0); BAR(); SCHEDB();
    BAR(); SCHEDB(); PRIO(1); MFMA_Q(1, 0); PRIO(0); BAR(); SCHEDB();
  }

#undef STAGE_A
#undef STAGE_B
#undef LOAD_A
#undef LOAD_B
#undef MM1
#undef MFMA_Q
#undef BAR
#undef SCHEDB
#undef PRIO

  // ---- epilogue: 4 quarter-passes through float T2[64][260], FULL unroll
  float* T2 = (float*)smem;
  __syncthreads();
#pragma unroll
  for (int p = 0; p < 4; ++p) {
    if (wm == (p >> 1)) {
      const int rbase = (p & 1) * 4;            // compile-time (full unroll)
#pragma unroll
      for (int rf = 0; rf < 4; ++rf)
#pragma unroll
        for (int cf = 0; cf < 4; ++cf)
#pragma unroll
          for (int r = 0; r < 4; ++r)
            T2[(rf * 16 + fq * 4 + r) * 260 + wn * 64 + cf * 16 + fm] =
                acc[rbase + rf][cf][r];
    }
    __syncthreads();
#pragma unroll
    for (int ii = 0; ii < 8; ++ii) {
      const int cid = t + ii * 512;              // 4096 float4 chunks
      const int row = cid >> 6, ch = cid & 63;
      *(float4*)(C + (m0 + p * 64 + row) * 1024 + n0 + ch * 4) =
          *(const float4*)(T2 + row * 260 + ch * 4);
    }
    __syncthreads();
  }
}

// ---------------------------------------------------------------------------
// num GEMM (per b,h: M=4096 N=128 K=128) + fused den + mala/LePE/gate.
// Half-tile epilogue (T = 64x136); row-pair bf16x4 epilogue.
// ---------------------------------------------------------------------------
__global__ __launch_bounds__(256, 2) void gemm_num(
    const bf16* __restrict__ QKVG, const bf16* __restrict__ kvTall,
    const float* __restrict__ ksum, const float* __restrict__ vsum,
    const float* __restrict__ lepe_w, const float* __restrict__ lepe_b,
    bf16* __restrict__ obuf)
{
  __shared__ __align__(16) char smem[17408];
  bf16* As = (bf16*)smem;
  bf16* Bs = (bf16*)(smem + 8192);
  bf16* T  = (bf16*)smem;                      // epilogue, 64 rows, stride 136
  __shared__ float sden[128], svsum[128], slb[128], sksum[128];
  __shared__ float slw[5][128];

  const int t = threadIdx.x;
  const int h = blockIdx.y, b = blockIdx.z;
  const int bh = b * 8 + h;
  const long m0 = (long)blockIdx.x * 128;
  const bf16* A  = QKVG + (long)b * 16777216 + m0 * 4096 + h * 128;
  const bf16* Bw = kvTall + (long)bh * 16384;

  if (t < 128) {
    sksum[t] = ksum[bh * 128 + t];
    svsum[t] = vsum[bh * 128 + t];
    slb[t]   = lepe_b[h * 128 + t];
#pragma unroll
    for (int j = 0; j < 5; ++j) slw[j][t] = lepe_w[(h * 128 + t) * 5 + j];
  }

  const int i0 = t, i1 = t + 256;
  const bf16* gA0 = A + (long)(i0 >> 2) * 4096 + (i0 & 3) * 8;
  const bf16* gA1 = A + (long)(i1 >> 2) * 4096 + (i1 & 3) * 8;
  const bf16* gB0 = Bw + (long)(i0 >> 2) * 128 + (i0 & 3) * 8;
  const bf16* gB1 = Bw + (long)(i1 >> 2) * 128 + (i1 & 3) * 8;
  bf16* lA0 = As + i0 * 8; bf16* lA1 = As + i1 * 8;
  bf16* lB0 = Bs + i0 * 8; bf16* lB1 = Bs + i1 * 8;

  const int lane = t & 63, wv = t >> 6;
  const int moff = (wv & 1) * 64, noff = (wv >> 1) * 64;
  const int fm = lane & 15, fq = lane >> 4;

  f32x4 acc[4][4] = {};
  float dacc = 0.f;

  for (int k0 = 0; k0 < 128; k0 += 32) {
    async_copy16(gA0, lA0); async_copy16(gA1, lA1);
    async_copy16(gB0, lB0); async_copy16(gB1, lB1);
    gA0 += 32; gA1 += 32; gB0 += 32; gB1 += 32;
    __syncthreads();
    bf16x8 af[4], bfv[4];
#pragma unroll
    for (int i = 0; i < 4; ++i) {
      af[i]  = *(const bf16x8*)(As + (moff + i * 16 + fm) * 32 + fq * 8);
      bfv[i] = *(const bf16x8*)(Bs + (noff + i * 16 + fm) * 32 + fq * 8);
    }
#pragma unroll
    for (int i = 0; i < 4; ++i)
#pragma unroll
      for (int j = 0; j < 4; ++j)
        acc[i][j] = __builtin_amdgcn_mfma_f32_16x16x32_bf16(af[i], bfv[j], acc[i][j], 0, 0, 0);
    if (t < 128) {                 // den partial: row t, k-chunk k0..k0+32
#pragma unroll
      for (int c8 = 0; c8 < 4; ++c8) {
        bf16x8 q8 = *(const bf16x8*)(As + t * 32 + c8 * 8);
#pragma unroll
        for (int e = 0; e < 8; ++e) dacc += (float)q8[e] * sksum[k0 + c8 * 8 + e];
      }
    }
    __syncthreads();
  }
  if (t < 128) sden[t] = dacc * kScale + 4096.0f;

  // row-pair epilogue: lanes 0-31 -> even row cols 0..127 (4/lane),
  // lanes 32-63 -> odd row.
  const int lane32 = lane & 31, rsel = lane >> 5, c4 = lane32 * 4;
  float wj[5][4], lbv[4];
#pragma unroll
  for (int j = 0; j < 5; ++j)
#pragma unroll
    for (int cc = 0; cc < 4; ++cc) wj[j][cc] = slw[j][c4 + cc];
#pragma unroll
  for (int cc = 0; cc < 4; ++cc) lbv[cc] = slb[c4 + cc];

#pragma unroll
  for (int half = 0; half < 2; ++half) {
    if ((wv & 1) == half) {
#pragma unroll
      for (int i = 0; i < 4; ++i)
#pragma unroll
        for (int j = 0; j < 4; ++j)
#pragma unroll
          for (int r = 0; r < 4; ++r) {
            const int col = noff + j * 16 + fm;
            T[(i * 16 + fq * 4 + r) * 136 + col] = (bf16)(acc[i][j][r] * kScale + svsum[col]);
          }
    }
    __syncthreads();   // covers T (and sden on first pass)
    for (int rr = 0; rr < 8; ++rr) {
      const int lrow = wv * 16 + rr * 2 + rsel;  // 0..63
      const int row = half * 64 + lrow;          // 0..127 within tile
      const int s = (int)(m0 + row);
      const long grow = (long)b * 4096 + s;
      const float rden = 1.0f / sden[row];
      const bf16* vrow = QKVG + grow * 4096 + 2048 + h * 128 + c4;
      bf16x4 a4v = *(const bf16x4*)(T + lrow * 136 + c4);
      float lep[4] = {lbv[0], lbv[1], lbv[2], lbv[3]};
#pragma unroll
      for (int jt = 0; jt < 5; ++jt) {
        const int srow = s + jt - 2;
        if (srow >= 0 && srow < 4096) {
          bf16x4 v4 = *(const bf16x4*)(vrow + (long)(jt - 2) * 4096);
#pragma unroll
          for (int cc = 0; cc < 4; ++cc) lep[cc] += (float)v4[cc] * wj[jt][cc];
        }
      }
      bf16x4 g4 = *(const bf16x4*)(QKVG + grow * 4096 + 3072 + h * 128 + c4);
      bf16x4 o4;
#pragma unroll
      for (int cc = 0; cc < 4; ++cc)
        o4[cc] = (bf16)(((float)a4v[cc] * rden + lep[cc]) * (float)g4[cc]);
      *(bf16x4*)(obuf + grow * 1024 + h * 128 + c4) = o4;
    }
    __syncthreads();
  }
}

// ---------------------------------------------------------------------------
// prep: cast X->bf16, cast/concat weights, build rope sin/cos table.
// ---------------------------------------------------------------------------
__global__ void prep_kernel(const float* __restrict__ X, const float* __restrict__ Wq,
                            const float* __restrict__ Wk, const float* __restrict__ Wv,
                            const float* __restrict__ Wg, const float* __restrict__ Wo,
                            bf16* __restrict__ Xb, bf16* __restrict__ Wcat,
                            bf16* __restrict__ Wob, float2* __restrict__ tab)
{
  const int blk = blockIdx.x;
  if (blk < 16384) {
    long g = ((long)blk * 256 + threadIdx.x) * 4;
    float4 v = *(const float4*)(X + g);
    bf16x4 o = {(bf16)v.x, (bf16)v.y, (bf16)v.z, (bf16)v.w};
    *(bf16x4*)(Xb + g) = o;
  } else if (blk < 21504) {
    long g = ((long)(blk - 16384) * 256 + threadIdx.x) * 4;
    if (g < 4194304) {
      long idx = g & 1048575;
      int sel = (int)(g >> 20);
      const float* s = sel == 0 ? Wq : sel == 1 ? Wk : sel == 2 ? Wv : Wg;
      float4 v = *(const float4*)(s + idx);
      bf16x4 o = {(bf16)v.x, (bf16)v.y, (bf16)v.z, (bf16)v.w};
      *(bf16x4*)(Wcat + g) = o;
    } else {
      long idx = g - 4194304;
      float4 v = *(const float4*)(Wo + idx);
      bf16x4 o = {(bf16)v.x, (bf16)v.y, (bf16)v.z, (bf16)v.w};
      *(bf16x4*)(Wob + idx) = o;
    }
  } else {
    int idx = (blk - 21504) * 256 + threadIdx.x;
    int s = idx >> 6, i = idx & 63;
    float inv = powf(10000.0f, -((float)(2 * i)) / 128.0f);
    float ang = (float)s * inv;
    float sn, cs;
    sincosf(ang, &sn, &cs);
    tab[idx] = make_float2(sn, cs);
  }
}

// ---------------------------------------------------------------------------
// kv via MFMA with in-LDS transpose. Grid (16, 32) = 512 blocks (2/CU).
// kvp[chunk][bh][e][d] = sum_s v[s][e] k[s][d]; + ksum/vsum partials.
// LDS layout VT/KT[f][40 s-slots]; 16B s-units XOR-swizzled by (f>>3)&3
// on write and fragment read (write conflicts 16-way -> 4-way). The rsum
// loop sums all units, so unit order is irrelevant there.
// ---------------------------------------------------------------------------
__global__ __launch_bounds__(256, 2) void kv_mfma(
    const bf16* __restrict__ QKVG, float* __restrict__ kvp,
    float* __restrict__ ksump, float* __restrict__ vsump)
{
  __shared__ __align__(16) bf16 VT[128 * 40];
  __shared__ __align__(16) bf16 KT[128 * 40];
  const int t = threadIdx.x;
  const int chunk = blockIdx.x, bh = blockIdx.y;
  const int b = bh >> 3, h = bh & 7;
  const long rowbase = ((long)b * 4096 + chunk * 256) * 4096 + h * 128;
  const bf16* Kg = QKVG + rowbase + 1024;
  const bf16* Vg = QKVG + rowbase + 2048;

  const int sp = t >> 4, fc = t & 15;
  const int lane = t & 63, wv = t >> 6;
  const int eoff = (wv & 1) * 64, doff = (wv >> 1) * 64;
  const int fm = lane & 15, fq = lane >> 4;
  const int srow = t & 127;
  const bool sumK = t >= 128;

  // swizzled write slot (bf16 index within row): unit ^= fc&3 (= (f>>3)&3)
  const int wslot = (((sp >> 2) ^ (fc & 3)) << 3) + (sp & 3) * 2;

  f32x4 acc[4][4] = {};
  float rsum = 0.f;

  for (int sb = 0; sb < 256; sb += 32) {
    const long go = (long)(sb + 2 * sp) * 4096 + fc * 8;
    bf16x8 v0 = *(const bf16x8*)(Vg + go);
    bf16x8 v1 = *(const bf16x8*)(Vg + go + 4096);
    bf16x8 k0 = *(const bf16x8*)(Kg + go);
    bf16x8 k1 = *(const bf16x8*)(Kg + go + 4096);
#pragma unroll
    for (int j = 0; j < 8; ++j) {
      const int f = fc * 8 + j;
      bf16x2 vp2 = {v0[j], v1[j]};
      bf16x2 kp2 = {k0[j], k1[j]};
      *(bf16x2*)(VT + f * 40 + wslot) = vp2;
      *(bf16x2*)(KT + f * 40 + wslot) = kp2;
    }
    __syncthreads();
    bf16x8 af[4], bfv[4];
#pragma unroll
    for (int i = 0; i < 4; ++i) {
      const int rowA = eoff + i * 16 + fm;
      const int rowB = doff + i * 16 + fm;
      af[i]  = *(const bf16x8*)(VT + rowA * 40 + ((fq ^ ((rowA >> 3) & 3)) << 3));
      bfv[i] = *(const bf16x8*)(KT + rowB * 40 + ((fq ^ ((rowB >> 3) & 3)) << 3));
    }
#pragma unroll
    for (int i = 0; i < 4; ++i)
#pragma unroll
      for (int j = 0; j < 4; ++j)
        acc[i][j] = __builtin_amdgcn_mfma_f32_16x16x32_bf16(af[i], bfv[j], acc[i][j], 0, 0, 0);
    const bf16* rp = (sumK ? KT : VT) + srow * 40;
#pragma unroll
    for (int i = 0; i < 4; ++i) {
      bf16x8 r8 = *(const bf16x8*)(rp + i * 8);   // physical units; sum-order free
#pragma unroll
      for (int j = 0; j < 8; ++j) rsum += (float)r8[j];
    }
    __syncthreads();
  }

  float* plane = kvp + ((long)chunk * 32 + bh) * 16384;
#pragma unroll
  for (int i = 0; i < 4; ++i)
#pragma unroll
    for (int j = 0; j < 4; ++j)
#pragma unroll
      for (int r = 0; r < 4; ++r)
        plane[(long)(eoff + i * 16 + fq * 4 + r) * 128 + (doff + j * 16 + fm)] = acc[i][j][r];
  float* sdst = (sumK ? ksump : vsump) + ((long)chunk * 32 + bh) * 128 + srow;
  *sdst = rsum;
}

// Fold 16 chunk partials -> bf16 kvT + f32 ksum/vsum. float4-vectorized.
__global__ void kv_reduce(const float* __restrict__ kvp, const float* __restrict__ ksump,
                          const float* __restrict__ vsump, bf16* __restrict__ kvT,
                          float* __restrict__ ksum, float* __restrict__ vsum)
{
  long g = (long)blockIdx.x * 256 + threadIdx.x;   // 0..131071 (512 blocks)
  long bh = g >> 12, idx4 = (g & 4095) * 4;
  const float* base = kvp + bh * 16384 + idx4;
  float4 s = make_float4(0.f, 0.f, 0.f, 0.f);
#pragma unroll
  for (int c = 0; c < 16; ++c) {
    float4 v = *(const float4*)(base + (long)c * 524288);
    s.x += v.x; s.y += v.y; s.z += v.z; s.w += v.w;
  }
  bf16x4 o = {(bf16)s.x, (bf16)s.y, (bf16)s.z, (bf16)s.w};
  *(bf16x4*)(kvT + bh * 16384 + idx4) = o;
  if (g < 8192) {
    int bh2 = (int)(g >> 8), rem = (int)(g & 255), f = rem & 127;
    const float* src = (rem >> 7) ? ksump : vsump;
    float* dst = (rem >> 7) ? ksum : vsum;
    float s2 = 0.f;
#pragma unroll
    for (int c = 0; c < 16; ++c) s2 += src[((long)c * 32 + bh2) * 128 + f];
    dst[bh2 * 128 + f] = s2;
  }
}

// ---------------------------------------------------------------------------
extern "C" void kernel_launch(void* const* d_in, const int* in_sizes, int n_in,
                              void* d_out, int out_size, void* d_ws, size_t ws_size,
                              hipStream_t stream)
{
  const float* X      = (const float*)d_in[0];
  const float* Wq     = (const float*)d_in[1];
  const float* Wk     = (const float*)d_in[2];
  const float* Wv     = (const float*)d_in[3];
  const float* Wg     = (const float*)d_in[4];
  const float* Wo     = (const float*)d_in[5];
  const float* lepe_w = (const float*)d_in[6];
  const float* lepe_b = (const float*)d_in[7];
  float* out = (float*)d_out;

  char* ws = (char*)d_ws;
  bf16*   Xb    = (bf16*)(ws);
  float*  kvp   = (float*)(ws);                  // aliases Xb (dead after proj)
  bf16*   Wcat  = (bf16*)(ws + 33554432);
  bf16*   Wob   = (bf16*)(ws + 41943040);
  float2* tab   = (float2*)(ws + 44040192);
  float*  ksump = (float*)(ws + 44040192);       // aliases tab (dead after proj)
  float*  vsump = (float*)(ws + 44302336);
  bf16*   QKVG  = (bf16*)(ws + 46137344);
  float*  ksum  = (float*)(ws + 180355072);
  float*  vsum  = (float*)(ws + 180371456);
  bf16*   kvT   = (bf16*)(ws + 180387840);
  bf16*   obuf  = (bf16*)(ws + 181960704);

  prep_kernel<<<22528, 256, 0, stream>>>(X, Wq, Wk, Wv, Wg, Wo, Xb, Wcat, Wob, tab);

  gemm_qkvg<<<1024, 512, 0, stream>>>(Xb, Wcat, QKVG, tab);

  kv_mfma<<<dim3(16, 32), 256, 0, stream>>>(QKVG, kvp, ksump, vsump);
  kv_reduce<<<512, 256, 0, stream>>>(kvp, ksump, vsump, kvT, ksum, vsum);

  gemm_num<<<dim3(32, 8, 4), 256, 0, stream>>>(QKVG, kvT, ksum, vsum, lepe_w, lepe_b, obuf);

  gemm_final<<<256, 512, 0, stream>>>(obuf, Wob, out);
}